// Round 5
// baseline (952.217 us; speedup 1.0000x reference)
//
#include <hip/hip_runtime.h>
#include <hip/hip_bf16.h>
#include <math.h>

#define CC0 2000
#define CC1 10000
#define CC2 50000
#define DH  1024
#define BATCH 4096
#define OUT_HEAD (CC0 + 2)

typedef __attribute__((ext_vector_type(4))) float  f32x4;
typedef __attribute__((ext_vector_type(8))) __bf16 bf16x8;
typedef __attribute__((ext_vector_type(8))) short  s16x8;

__device__ __forceinline__ void gload_lds16(const void* g, void* l) {
    __builtin_amdgcn_global_load_lds(
        (const __attribute__((address_space(1))) void*)g,
        (__attribute__((address_space(3))) void*)l, 16, 0, 0);
}

// ---------------- all fp32 -> bf16 conversions in one launch (6 segments) ----------
__global__ __launch_bounds__(256) void convert_all_kernel(
    const float4* __restrict__ s0, ushort4* __restrict__ d0, int n0s, int n0d,
    const float4* __restrict__ s1, ushort4* __restrict__ d1, int n1s, int n1d,
    const float4* __restrict__ s2, ushort4* __restrict__ d2, int n2s, int n2d,
    const float4* __restrict__ s3, ushort4* __restrict__ d3, int n3s, int n3d,
    const float4* __restrict__ s4, ushort4* __restrict__ d4, int n4s, int n4d,
    const float4* __restrict__ s5, ushort4* __restrict__ d5, int n5s, int n5d)
{
    const float4* src; ushort4* dst; int ns, nd;
    switch (blockIdx.y) {
        case 0: src = s0; dst = d0; ns = n0s; nd = n0d; break;
        case 1: src = s1; dst = d1; ns = n1s; nd = n1d; break;
        case 2: src = s2; dst = d2; ns = n2s; nd = n2d; break;
        case 3: src = s3; dst = d3; ns = n3s; nd = n3d; break;
        case 4: src = s4; dst = d4; ns = n4s; nd = n4d; break;
        default: src = s5; dst = d5; ns = n5s; nd = n5d; break;
    }
    int i = blockIdx.x * blockDim.x + threadIdx.x;
    const int stride = gridDim.x * blockDim.x;
    for (; i < nd; i += stride) {
        ushort4 o = {0, 0, 0, 0};
        if (i < ns) {
            float4 v = src[i];
            o.x = __builtin_bit_cast(unsigned short, (__bf16)v.x);
            o.y = __builtin_bit_cast(unsigned short, (__bf16)v.y);
            o.z = __builtin_bit_cast(unsigned short, (__bf16)v.z);
            o.w = __builtin_bit_cast(unsigned short, (__bf16)v.w);
        }
        dst[i] = o;
    }
}

// ---------------- zero row-sum accumulators ----------------
__global__ __launch_bounds__(256) void zero_kernel(float* __restrict__ a,
                                                   float* __restrict__ b, int n) {
    int i = blockIdx.x * blockDim.x + threadIdx.x;
    if (i < n) { a[i] = 0.f; b[i] = 0.f; }
}

// ---------------- 128x128 MFMA GEMM (m97 structure): C[M,N] = A[M,K] * B[N,K]^T ----
// WMODE: 0 = no C write, 1 = bf16 C, 2 = f32 C, 3 = f32 C + addv[row] (normalized)
// 4 waves (2x2), 64x64 per wave via 4x4 mfma_16x16x32 fragments, BK=64,
// global_load_lds width-16, linear LDS. M%128==0, K%64==0, B zero-padded rows.
template <int WMODE, bool SUMEXP>
__global__ __launch_bounds__(256) void gemm128_kernel(
    const ushort* __restrict__ A, const ushort* __restrict__ B,
    void* __restrict__ Cp, int M, int N, int K, int ldC,
    float* __restrict__ rowsum, const float* __restrict__ addv)
{
    __shared__ ushort As[128 * 64];
    __shared__ ushort Bs[128 * 64];

    // bijective XCD swizzle (all launches have nwg % 8 == 0)
    const int nwg = gridDim.x * gridDim.y;
    const int q = nwg >> 3;
    int bid = blockIdx.y * gridDim.x + blockIdx.x;
    bid = (bid & 7) * q + (bid >> 3);
    const int bx = bid % gridDim.x;
    const int by = bid / gridDim.x;

    const int t = threadIdx.x;
    const int lane = t & 63;
    const int w = t >> 6;
    const int wr = w >> 1, wc = w & 1;
    const int lr = lane & 15;       // input frag row / C col
    const int lg = lane >> 4;       // input k-group / C row-group
    const int bm = by * 128;
    const int bn = bx * 128;

    const int lrow = lane >> 3;          // 0..7 within a 1KB segment
    const int lcol = (lane & 7) * 8;     // element col within BK=64

    f32x4 acc[4][4] = {};

    for (int k0 = 0; k0 < K; k0 += 64) {
        #pragma unroll
        for (int i = 0; i < 4; ++i) {
            const int seg = w * 4 + i;                // 0..15, wave-uniform
            const int row = seg * 8 + lrow;           // 0..127
            gload_lds16(A + (size_t)(bm + row) * K + k0 + lcol, &As[seg * 512]);
            gload_lds16(B + (size_t)(bn + row) * K + k0 + lcol, &Bs[seg * 512]);
        }
        __syncthreads();
        #pragma unroll
        for (int ks = 0; ks < 2; ++ks) {
            s16x8 af[4], bfr[4];
            #pragma unroll
            for (int m = 0; m < 4; ++m)
                af[m] = *(const s16x8*)&As[(wr * 64 + m * 16 + lr) * 64 + ks * 32 + lg * 8];
            #pragma unroll
            for (int n = 0; n < 4; ++n)
                bfr[n] = *(const s16x8*)&Bs[(wc * 64 + n * 16 + lr) * 64 + ks * 32 + lg * 8];
            #pragma unroll
            for (int m = 0; m < 4; ++m)
                #pragma unroll
                for (int n = 0; n < 4; ++n)
                    acc[m][n] = __builtin_amdgcn_mfma_f32_16x16x32_bf16(
                        __builtin_bit_cast(bf16x8, af[m]),
                        __builtin_bit_cast(bf16x8, bfr[n]), acc[m][n], 0, 0, 0);
        }
        __syncthreads();
    }

    // epilogue: row = bm + wr*64 + m*16 + lg*4 + r;  col = bn + wc*64 + n*16 + lr
    #pragma unroll
    for (int m = 0; m < 4; ++m) {
        #pragma unroll
        for (int r = 0; r < 4; ++r) {
            const int row = bm + wr * 64 + m * 16 + lg * 4 + r;
            const float addr_ = (WMODE == 3) ? addv[row] : 0.f;
            float psum = 0.f;
            #pragma unroll
            for (int n = 0; n < 4; ++n) {
                const int col = bn + wc * 64 + n * 16 + lr;
                float v = acc[m][n][r];
                if (col < N) {
                    if (WMODE == 1)
                        ((ushort*)Cp)[(size_t)row * ldC + col] =
                            __builtin_bit_cast(unsigned short, (__bf16)v);
                    else if (WMODE == 2)
                        ((float*)Cp)[(size_t)row * ldC + col] = v;
                    else if (WMODE == 3)
                        ((float*)Cp)[(size_t)row * ldC + col] = v + addr_;
                    if (SUMEXP) psum += __expf(v);  // logits O(1): max-free LSE safe
                }
            }
            if (SUMEXP) {
                #pragma unroll
                for (int mm = 1; mm < 16; mm <<= 1) psum += __shfl_xor(psum, mm, 64);
                if (lr == 0) atomicAdd(&rowsum[row], psum);
            }
        }
    }
}

// ---------------- head log-softmax: one block per row ----------------
__global__ __launch_bounds__(256) void head_lsm_kernel(
    const float* __restrict__ HL, const float* __restrict__ bh,
    float* __restrict__ out, float* __restrict__ s01)
{
    const int row = blockIdx.x;
    const float* L = HL + (size_t)row * OUT_HEAD;
    const int t = threadIdx.x;
    __shared__ float red[4];

    float m = -1e30f;
    for (int i = t; i < OUT_HEAD; i += 256) m = fmaxf(m, L[i] + bh[i]);
    #pragma unroll
    for (int s = 1; s < 64; s <<= 1) m = fmaxf(m, __shfl_xor(m, s, 64));
    if ((t & 63) == 0) red[t >> 6] = m;
    __syncthreads();
    m = fmaxf(fmaxf(red[0], red[1]), fmaxf(red[2], red[3]));

    float sum = 0.f;
    for (int i = t; i < OUT_HEAD; i += 256) sum += __expf(L[i] + bh[i] - m);
    #pragma unroll
    for (int s = 1; s < 64; s <<= 1) sum += __shfl_xor(sum, s, 64);
    __syncthreads();
    if ((t & 63) == 0) red[t >> 6] = sum;
    __syncthreads();
    const float lse = m + logf(red[0] + red[1] + red[2] + red[3]);

    float* orow = out + (size_t)row * CC2;
    for (int i = t; i < CC0; i += 256) orow[i] = L[i] + bh[i] - lse;
    if (t == 0) {
        s01[2 * row + 0] = L[CC0 + 0] + bh[CC0 + 0] - lse;
        s01[2 * row + 1] = L[CC0 + 1] + bh[CC0 + 1] - lse;
    }
}

// ---------------- per-row additive constants: add = s01 - log(rowsum) ----------------
__global__ __launch_bounds__(256) void prep_add_kernel(
    const float* __restrict__ s01, const float* __restrict__ rs0,
    const float* __restrict__ rs1, float* __restrict__ add0,
    float* __restrict__ add1, int n)
{
    int i = blockIdx.x * blockDim.x + threadIdx.x;
    if (i < n) {
        add0[i] = s01[2 * i + 0] - logf(rs0[i]);
        add1[i] = s01[2 * i + 1] - logf(rs1[i]);
    }
}

// ---------------- finalize tail0 from bf16 logits: out = bf16logit + add0[row] ----------
__global__ __launch_bounds__(256) void finalize_bf16_kernel(
    const ushort* __restrict__ Lg, int ldL, int ncols8,
    float* __restrict__ outb, const float* __restrict__ addv)
{
    const int row = blockIdx.y;
    const float add = addv[row];
    const int c = blockIdx.x * blockDim.x + threadIdx.x;
    if (c >= ncols8) return;
    s16x8 v = *(const s16x8*)(Lg + (size_t)row * ldL + c * 8);
    float* o = outb + (size_t)row * CC2 + c * 8;
    float4 o0, o1;
    o0.x = __builtin_bit_cast(float, (unsigned)(unsigned short)v[0] << 16) + add;
    o0.y = __builtin_bit_cast(float, (unsigned)(unsigned short)v[1] << 16) + add;
    o0.z = __builtin_bit_cast(float, (unsigned)(unsigned short)v[2] << 16) + add;
    o0.w = __builtin_bit_cast(float, (unsigned)(unsigned short)v[3] << 16) + add;
    o1.x = __builtin_bit_cast(float, (unsigned)(unsigned short)v[4] << 16) + add;
    o1.y = __builtin_bit_cast(float, (unsigned)(unsigned short)v[5] << 16) + add;
    o1.z = __builtin_bit_cast(float, (unsigned)(unsigned short)v[6] << 16) + add;
    o1.w = __builtin_bit_cast(float, (unsigned)(unsigned short)v[7] << 16) + add;
    *(float4*)o = o0;
    *(float4*)(o + 4) = o1;
}

// ---------------- launch ----------------
extern "C" void kernel_launch(void* const* d_in, const int* in_sizes, int n_in,
                              void* d_out, int out_size, void* d_ws, size_t ws_size,
                              hipStream_t stream) {
    const float* x   = (const float*)d_in[0];
    const float* Wh  = (const float*)d_in[1];
    const float* bh  = (const float*)d_in[2];
    const float* W0a = (const float*)d_in[3];
    const float* W0b = (const float*)d_in[4];
    const float* W1a = (const float*)d_in[5];
    const float* W1b = (const float*)d_in[6];
    float* out = (float*)d_out;
    char*  ws  = (char*)d_ws;

    // padded row counts (multiples of 128)
    const int NH_P  = 2048;    // head rows (2002 -> 2048)
    const int N0_P  = 8064;    // tail0 proj rows (8000 -> 8064)
    const int N1_P  = 40064;   // tail1 proj rows (40000 -> 40064)

    size_t off = 0;
    auto alloc = [&](size_t bytes) { size_t o = off; off += (bytes + 255) & ~(size_t)255; return o; };
    ushort* x_bf   = (ushort*)(ws + alloc((size_t)BATCH * DH * 2));
    ushort* Wh_bf  = (ushort*)(ws + alloc((size_t)NH_P * DH * 2));
    ushort* W0a_bf = (ushort*)(ws + alloc((size_t)DH * DH * 2));
    ushort* W0b_bf = (ushort*)(ws + alloc((size_t)N0_P * DH * 2));
    ushort* W1a_bf = (ushort*)(ws + alloc((size_t)256 * DH * 2));
    ushort* W1b_bf = (ushort*)(ws + alloc((size_t)N1_P * 256 * 2));
    ushort* h0_bf  = (ushort*)(ws + alloc((size_t)BATCH * DH * 2));
    ushort* h1_bf  = (ushort*)(ws + alloc((size_t)BATCH * 256 * 2));
    float*  headL  = (float*)(ws + alloc((size_t)BATCH * OUT_HEAD * 4));
    float*  s01    = (float*)(ws + alloc((size_t)BATCH * 2 * 4));
    float*  rs0    = (float*)(ws + alloc((size_t)BATCH * 4));
    float*  rs1    = (float*)(ws + alloc((size_t)BATCH * 4));
    float*  add0   = (float*)(ws + alloc((size_t)BATCH * 4));
    float*  add1   = (float*)(ws + alloc((size_t)BATCH * 4));
    ushort* L0     = (ushort*)(ws + alloc((size_t)BATCH * N0_P * 2));  // tail0 bf16 logits

    // one conversion launch for all 6 tensors
    convert_all_kernel<<<dim3(1280, 6), 256, 0, stream>>>(
        (const float4*)x,   (ushort4*)x_bf,   BATCH * DH / 4,        BATCH * DH / 4,
        (const float4*)Wh,  (ushort4*)Wh_bf,  OUT_HEAD * DH / 4,     NH_P * DH / 4,
        (const float4*)W0a, (ushort4*)W0a_bf, DH * DH / 4,           DH * DH / 4,
        (const float4*)W0b, (ushort4*)W0b_bf, (CC1 - CC0) * DH / 4,  N0_P * DH / 4,
        (const float4*)W1a, (ushort4*)W1a_bf, 256 * DH / 4,          256 * DH / 4,
        (const float4*)W1b, (ushort4*)W1b_bf, (CC2 - CC1) * 256 / 4, N1_P * 256 / 4);

    zero_kernel<<<(BATCH + 255) / 256, 256, 0, stream>>>(rs0, rs1, BATCH);

    // h0 = x @ W0a^T (bf16), h1 = x @ W1a^T (bf16)
    gemm128_kernel<1, false><<<dim3(DH / 128, BATCH / 128), 256, 0, stream>>>(
        x_bf, W0a_bf, h0_bf, BATCH, DH, DH, DH, nullptr, nullptr);
    gemm128_kernel<1, false><<<dim3(256 / 128, BATCH / 128), 256, 0, stream>>>(
        x_bf, W1a_bf, h1_bf, BATCH, 256, DH, 256, nullptr, nullptr);
    // head logits (fp32, ws)
    gemm128_kernel<2, false><<<dim3(NH_P / 128, BATCH / 128), 256, 0, stream>>>(
        x_bf, Wh_bf, headL, BATCH, OUT_HEAD, DH, OUT_HEAD, nullptr, nullptr);
    // head log-softmax -> out[:, :2000] + cluster scalars
    head_lsm_kernel<<<BATCH, 256, 0, stream>>>(headL, bh, out, s01);
    // tail0: bf16 logits (ws) + rowsum       tail1 pass1: rowsum only, no store
    gemm128_kernel<1, true><<<dim3(N0_P / 128, BATCH / 128), 256, 0, stream>>>(
        h0_bf, W0b_bf, L0, BATCH, CC1 - CC0, DH, N0_P, rs0, nullptr);
    gemm128_kernel<0, true><<<dim3(N1_P / 128, BATCH / 128), 256, 0, stream>>>(
        h1_bf, W1b_bf, nullptr, BATCH, CC2 - CC1, 256, 0, rs1, nullptr);
    // per-row additive constants
    prep_add_kernel<<<(BATCH + 255) / 256, 256, 0, stream>>>(s01, rs0, rs1, add0, add1, BATCH);
    // tail1 pass2: recompute GEMM, write normalized fp32 directly to out
    gemm128_kernel<3, false><<<dim3(N1_P / 128, BATCH / 128), 256, 0, stream>>>(
        h1_bf, W1b_bf, out + CC1, BATCH, CC2 - CC1, 256, CC2, nullptr, add1);
    // tail0: bf16 logits -> fp32 out with additive correction
    finalize_bf16_kernel<<<dim3((1000 + 255) / 256, BATCH), 256, 0, stream>>>(
        L0, N0_P, 1000, out + CC0, add0);
}

// Round 6
// 830.891 us; speedup vs baseline: 1.1460x; 1.1460x over previous
//
#include <hip/hip_runtime.h>
#include <hip/hip_bf16.h>
#include <math.h>

#define CC0 2000
#define CC1 10000
#define CC2 50000
#define DH  1024
#define BATCH 4096
#define OUT_HEAD (CC0 + 2)

typedef __attribute__((ext_vector_type(4))) float  f32x4;
typedef __attribute__((ext_vector_type(8))) __bf16 bf16x8;
typedef __attribute__((ext_vector_type(8))) short  s16x8;

__device__ __forceinline__ void gload_lds16(const void* g, void* l) {
    __builtin_amdgcn_global_load_lds(
        (const __attribute__((address_space(1))) void*)g,
        (__attribute__((address_space(3))) void*)l, 16, 0, 0);
}

// ---------------- all fp32 -> bf16 conversions in one launch (6 segments) ----------
__global__ __launch_bounds__(256) void convert_all_kernel(
    const float4* __restrict__ s0, ushort4* __restrict__ d0, int n0s, int n0d,
    const float4* __restrict__ s1, ushort4* __restrict__ d1, int n1s, int n1d,
    const float4* __restrict__ s2, ushort4* __restrict__ d2, int n2s, int n2d,
    const float4* __restrict__ s3, ushort4* __restrict__ d3, int n3s, int n3d,
    const float4* __restrict__ s4, ushort4* __restrict__ d4, int n4s, int n4d,
    const float4* __restrict__ s5, ushort4* __restrict__ d5, int n5s, int n5d)
{
    const float4* src; ushort4* dst; int ns, nd;
    switch (blockIdx.y) {
        case 0: src = s0; dst = d0; ns = n0s; nd = n0d; break;
        case 1: src = s1; dst = d1; ns = n1s; nd = n1d; break;
        case 2: src = s2; dst = d2; ns = n2s; nd = n2d; break;
        case 3: src = s3; dst = d3; ns = n3s; nd = n3d; break;
        case 4: src = s4; dst = d4; ns = n4s; nd = n4d; break;
        default: src = s5; dst = d5; ns = n5s; nd = n5d; break;
    }
    int i = blockIdx.x * blockDim.x + threadIdx.x;
    const int stride = gridDim.x * blockDim.x;
    for (; i < nd; i += stride) {
        ushort4 o = {0, 0, 0, 0};
        if (i < ns) {
            float4 v = src[i];
            o.x = __builtin_bit_cast(unsigned short, (__bf16)v.x);
            o.y = __builtin_bit_cast(unsigned short, (__bf16)v.y);
            o.z = __builtin_bit_cast(unsigned short, (__bf16)v.z);
            o.w = __builtin_bit_cast(unsigned short, (__bf16)v.w);
        }
        dst[i] = o;
    }
}

// ---------------- zero row-sum accumulators ----------------
__global__ __launch_bounds__(256) void zero_kernel(float* __restrict__ a,
                                                   float* __restrict__ b, int n) {
    int i = blockIdx.x * blockDim.x + threadIdx.x;
    if (i < n) { a[i] = 0.f; b[i] = 0.f; }
}

// ---------------- 128x128 MFMA GEMM (m97 structure) for small GEMMs --------------
// WMODE: 1 = bf16 C, 2 = f32 C
template <int WMODE>
__global__ __launch_bounds__(256) void gemm128_kernel(
    const ushort* __restrict__ A, const ushort* __restrict__ B,
    void* __restrict__ Cp, int M, int N, int K, int ldC)
{
    __shared__ ushort As[128 * 64];
    __shared__ ushort Bs[128 * 64];

    const int nwg = gridDim.x * gridDim.y;
    const int q = nwg >> 3;
    int bid = blockIdx.y * gridDim.x + blockIdx.x;
    bid = (bid & 7) * q + (bid >> 3);
    const int bx = bid % gridDim.x;
    const int by = bid / gridDim.x;

    const int t = threadIdx.x;
    const int lane = t & 63;
    const int w = t >> 6;
    const int wr = w >> 1, wc = w & 1;
    const int lr = lane & 15;
    const int lg = lane >> 4;
    const int bm = by * 128;
    const int bn = bx * 128;
    const int lrow = lane >> 3;
    const int lcol = (lane & 7) * 8;

    f32x4 acc[4][4] = {};

    for (int k0 = 0; k0 < K; k0 += 64) {
        #pragma unroll
        for (int i = 0; i < 4; ++i) {
            const int seg = w * 4 + i;
            const int row = seg * 8 + lrow;
            gload_lds16(A + (size_t)(bm + row) * K + k0 + lcol, &As[seg * 512]);
            gload_lds16(B + (size_t)(bn + row) * K + k0 + lcol, &Bs[seg * 512]);
        }
        __syncthreads();
        #pragma unroll
        for (int ks = 0; ks < 2; ++ks) {
            s16x8 af[4], bfr[4];
            #pragma unroll
            for (int m = 0; m < 4; ++m)
                af[m] = *(const s16x8*)&As[(wr * 64 + m * 16 + lr) * 64 + ks * 32 + lg * 8];
            #pragma unroll
            for (int n = 0; n < 4; ++n)
                bfr[n] = *(const s16x8*)&Bs[(wc * 64 + n * 16 + lr) * 64 + ks * 32 + lg * 8];
            #pragma unroll
            for (int m = 0; m < 4; ++m)
                #pragma unroll
                for (int n = 0; n < 4; ++n)
                    acc[m][n] = __builtin_amdgcn_mfma_f32_16x16x32_bf16(
                        __builtin_bit_cast(bf16x8, af[m]),
                        __builtin_bit_cast(bf16x8, bfr[n]), acc[m][n], 0, 0, 0);
        }
        __syncthreads();
    }

    #pragma unroll
    for (int m = 0; m < 4; ++m) {
        #pragma unroll
        for (int r = 0; r < 4; ++r) {
            const int row = bm + wr * 64 + m * 16 + lg * 4 + r;
            #pragma unroll
            for (int n = 0; n < 4; ++n) {
                const int col = bn + wc * 64 + n * 16 + lr;
                float v = acc[m][n][r];
                if (col < N) {
                    if (WMODE == 1)
                        ((ushort*)Cp)[(size_t)row * ldC + col] =
                            __builtin_bit_cast(unsigned short, (__bf16)v);
                    else
                        ((float*)Cp)[(size_t)row * ldC + col] = v;
                }
            }
        }
    }
}

// ---------------- 256x256 8-phase MFMA GEMM (m201 structure) ----------------------
// WMODE: 0 = no C write, 1 = bf16 C, 3 = f32 C + addv[row]
// 8 waves (2Mx4N), 512 threads; wave = 128x64 out via 8x4 16x16x32 frags; BK=64.
// LDS 128 KiB double-buffered; XOR swizzle byte^=((row&7)<<4) applied as
// pre-swizzled global source (linear global_load_lds dest) + swizzled ds_read.
template <int WMODE, bool SUMEXP>
__global__ __launch_bounds__(512, 1) void gemm256_kernel(
    const ushort* __restrict__ A, const ushort* __restrict__ B,
    void* __restrict__ Cp, int M, int N, int K, int ldC,
    float* __restrict__ rowsum, const float* __restrict__ addv)
{
    __shared__ ushort lds[2][2][256 * 64];   // [buf][A/B][row*64+col] = 128 KiB

    const int nwg = gridDim.x * gridDim.y;
    const int q8 = nwg >> 3;
    int bid = blockIdx.y * gridDim.x + blockIdx.x;
    bid = (bid & 7) * q8 + (bid >> 3);
    const int bx = bid % gridDim.x;
    const int by = bid / gridDim.x;
    const int bm = by * 256, bn = bx * 256;

    const int t = threadIdx.x;
    const int lane = t & 63;
    const int w = t >> 6;        // 0..7
    const int wr = w >> 2;       // 0..1  (M half)
    const int wc = w & 3;        // 0..3  (N quarter)
    const int lr = lane & 15;
    const int lg = lane >> 4;
    const int xr = (lr & 7) << 4;          // read-side XOR (bits 4-6)

    // staging source decomposition for chunk c = i*512 + w*64 + lane (per half):
    const int c0 = w * 64 + lane;          // i=0 chunk
    // rl = c>>3 (local row 0..127), colchunk = (c&7) ^ (rl&7)
    f32x4 acc[8][4] = {};

    const int nkt = K / 64;

    // ---- prologue: stage K-tile 0 (4 halves x 2 loads) into buf 0
    #pragma unroll
    for (int h = 0; h < 4; ++h) {
        const int r0 = (h >> 1) * 128;
        const int mat = h & 1;
        const ushort* base = mat ? B : A;
        const int brow = mat ? bn : bm;
        #pragma unroll
        for (int i = 0; i < 2; ++i) {
            const int c = i * 512 + c0;
            const int rl = c >> 3;
            const int cc = (c & 7) ^ (rl & 7);
            gload_lds16(base + (size_t)(brow + r0 + rl) * K + cc * 8,
                        (char*)&lds[0][mat][0] + r0 * 128 + (i * 512 + w * 64) * 16);
        }
    }
    asm volatile("s_waitcnt vmcnt(0)");
    __builtin_amdgcn_s_barrier();
    asm volatile("" ::: "memory");

    for (int tk = 0; tk < nkt; ++tk) {
        const int cur = tk & 1;
        const int nxt = cur ^ 1;
        const int k1 = (tk + 1) * 64;
        const char* baseA = (const char*)&lds[cur][0][0];
        const char* baseB = (const char*)&lds[cur][1][0];
        #pragma unroll
        for (int q = 0; q < 4; ++q) {
            const int mh = q >> 1, nh = q & 1;
            // ---- ds-read register subtile (8 A + 4 B ds_read_b128)
            s16x8 af[4][2], bf_[2][2];
            #pragma unroll
            for (int m_ = 0; m_ < 4; ++m_) {
                const int row = wr * 128 + (mh * 4 + m_) * 16 + lr;
                #pragma unroll
                for (int ks = 0; ks < 2; ++ks)
                    af[m_][ks] = *(const s16x8*)(baseA + (row * 128 + ((ks * 64 + lg * 16) ^ xr)));
            }
            #pragma unroll
            for (int n_ = 0; n_ < 2; ++n_) {
                const int row = wc * 64 + (nh * 2 + n_) * 16 + lr;
                #pragma unroll
                for (int ks = 0; ks < 2; ++ks)
                    bf_[n_][ks] = *(const s16x8*)(baseB + (row * 128 + ((ks * 64 + lg * 16) ^ xr)));
            }
            // ---- stage half q of K-tile tk+1 into other buffer
            if (tk + 1 < nkt) {
                const int r0 = (q >> 1) * 128;
                const int mat = q & 1;
                const ushort* gbase = mat ? B : A;
                const int brow = mat ? bn : bm;
                #pragma unroll
                for (int i = 0; i < 2; ++i) {
                    const int c = i * 512 + c0;
                    const int rl = c >> 3;
                    const int cc = (c & 7) ^ (rl & 7);
                    gload_lds16(gbase + (size_t)(brow + r0 + rl) * K + k1 + cc * 8,
                                (char*)&lds[nxt][mat][0] + r0 * 128 + (i * 512 + w * 64) * 16);
                }
            }
            __builtin_amdgcn_s_barrier();
            asm volatile("" ::: "memory");
            __builtin_amdgcn_s_setprio(1);
            #pragma unroll
            for (int m_ = 0; m_ < 4; ++m_)
                #pragma unroll
                for (int n_ = 0; n_ < 2; ++n_)
                    #pragma unroll
                    for (int ks = 0; ks < 2; ++ks)
                        acc[mh * 4 + m_][nh * 2 + n_] = __builtin_amdgcn_mfma_f32_16x16x32_bf16(
                            __builtin_bit_cast(bf16x8, af[m_][ks]),
                            __builtin_bit_cast(bf16x8, bf_[n_][ks]),
                            acc[mh * 4 + m_][nh * 2 + n_], 0, 0, 0);
            __builtin_amdgcn_s_setprio(0);
            if (q == 3) asm volatile("s_waitcnt vmcnt(0)");   // all 8 next-tile loads landed
            __builtin_amdgcn_s_barrier();
            asm volatile("" ::: "memory");
        }
    }

    // ---- epilogue: row = bm + wr*128 + m*16 + lg*4 + r; col = bn + wc*64 + n*16 + lr
    #pragma unroll
    for (int m = 0; m < 8; ++m) {
        #pragma unroll
        for (int r = 0; r < 4; ++r) {
            const int row = bm + wr * 128 + m * 16 + lg * 4 + r;
            const float addr_ = (WMODE == 3) ? addv[row] : 0.f;
            float psum = 0.f;
            #pragma unroll
            for (int n = 0; n < 4; ++n) {
                const int col = bn + wc * 64 + n * 16 + lr;
                float v = acc[m][n][r];
                if (col < N) {
                    if (WMODE == 1)
                        ((ushort*)Cp)[(size_t)row * ldC + col] =
                            __builtin_bit_cast(unsigned short, (__bf16)v);
                    else if (WMODE == 3)
                        ((float*)Cp)[(size_t)row * ldC + col] = v + addr_;
                    if (SUMEXP) psum += __expf(v);   // logits O(1): max-free LSE safe
                }
            }
            if (SUMEXP) {
                #pragma unroll
                for (int mm = 1; mm < 16; mm <<= 1) psum += __shfl_xor(psum, mm, 64);
                if (lr == 0) atomicAdd(&rowsum[row], psum);
            }
        }
    }
}

// ---------------- head log-softmax: one block per row ----------------
__global__ __launch_bounds__(256) void head_lsm_kernel(
    const float* __restrict__ HL, const float* __restrict__ bh,
    float* __restrict__ out, float* __restrict__ s01)
{
    const int row = blockIdx.x;
    const float* L = HL + (size_t)row * OUT_HEAD;
    const int t = threadIdx.x;
    __shared__ float red[4];

    float m = -1e30f;
    for (int i = t; i < OUT_HEAD; i += 256) m = fmaxf(m, L[i] + bh[i]);
    #pragma unroll
    for (int s = 1; s < 64; s <<= 1) m = fmaxf(m, __shfl_xor(m, s, 64));
    if ((t & 63) == 0) red[t >> 6] = m;
    __syncthreads();
    m = fmaxf(fmaxf(red[0], red[1]), fmaxf(red[2], red[3]));

    float sum = 0.f;
    for (int i = t; i < OUT_HEAD; i += 256) sum += __expf(L[i] + bh[i] - m);
    #pragma unroll
    for (int s = 1; s < 64; s <<= 1) sum += __shfl_xor(sum, s, 64);
    __syncthreads();
    if ((t & 63) == 0) red[t >> 6] = sum;
    __syncthreads();
    const float lse = m + logf(red[0] + red[1] + red[2] + red[3]);

    float* orow = out + (size_t)row * CC2;
    for (int i = t; i < CC0; i += 256) orow[i] = L[i] + bh[i] - lse;
    if (t == 0) {
        s01[2 * row + 0] = L[CC0 + 0] + bh[CC0 + 0] - lse;
        s01[2 * row + 1] = L[CC0 + 1] + bh[CC0 + 1] - lse;
    }
}

// ---------------- per-row additive constants: add = s01 - log(rowsum) ----------------
__global__ __launch_bounds__(256) void prep_add_kernel(
    const float* __restrict__ s01, const float* __restrict__ rs0,
    const float* __restrict__ rs1, float* __restrict__ add0,
    float* __restrict__ add1, int n)
{
    int i = blockIdx.x * blockDim.x + threadIdx.x;
    if (i < n) {
        add0[i] = s01[2 * i + 0] - logf(rs0[i]);
        add1[i] = s01[2 * i + 1] - logf(rs1[i]);
    }
}

// ---------------- finalize tail0 from bf16 logits: out = bf16logit + add0[row] ----------
__global__ __launch_bounds__(256) void finalize_bf16_kernel(
    const ushort* __restrict__ Lg, int ldL, int ncols8,
    float* __restrict__ outb, const float* __restrict__ addv)
{
    const int row = blockIdx.y;
    const float add = addv[row];
    const int c = blockIdx.x * blockDim.x + threadIdx.x;
    if (c >= ncols8) return;
    s16x8 v = *(const s16x8*)(Lg + (size_t)row * ldL + c * 8);
    float* o = outb + (size_t)row * CC2 + c * 8;
    float4 o0, o1;
    o0.x = __builtin_bit_cast(float, (unsigned)(unsigned short)v[0] << 16) + add;
    o0.y = __builtin_bit_cast(float, (unsigned)(unsigned short)v[1] << 16) + add;
    o0.z = __builtin_bit_cast(float, (unsigned)(unsigned short)v[2] << 16) + add;
    o0.w = __builtin_bit_cast(float, (unsigned)(unsigned short)v[3] << 16) + add;
    o1.x = __builtin_bit_cast(float, (unsigned)(unsigned short)v[4] << 16) + add;
    o1.y = __builtin_bit_cast(float, (unsigned)(unsigned short)v[5] << 16) + add;
    o1.z = __builtin_bit_cast(float, (unsigned)(unsigned short)v[6] << 16) + add;
    o1.w = __builtin_bit_cast(float, (unsigned)(unsigned short)v[7] << 16) + add;
    *(float4*)o = o0;
    *(float4*)(o + 4) = o1;
}

// ---------------- launch ----------------
extern "C" void kernel_launch(void* const* d_in, const int* in_sizes, int n_in,
                              void* d_out, int out_size, void* d_ws, size_t ws_size,
                              hipStream_t stream) {
    const float* x   = (const float*)d_in[0];
    const float* Wh  = (const float*)d_in[1];
    const float* bh  = (const float*)d_in[2];
    const float* W0a = (const float*)d_in[3];
    const float* W0b = (const float*)d_in[4];
    const float* W1a = (const float*)d_in[5];
    const float* W1b = (const float*)d_in[6];
    float* out = (float*)d_out;
    char*  ws  = (char*)d_ws;

    // padded row counts
    const int NH_P  = 2048;    // head rows, mult of 128
    const int N0_P  = 8192;    // tail0 proj rows, mult of 256
    const int N1_P  = 40192;   // tail1 proj rows, mult of 256 (157 tiles)

    size_t off = 0;
    auto alloc = [&](size_t bytes) { size_t o = off; off += (bytes + 255) & ~(size_t)255; return o; };
    ushort* x_bf   = (ushort*)(ws + alloc((size_t)BATCH * DH * 2));
    ushort* Wh_bf  = (ushort*)(ws + alloc((size_t)NH_P * DH * 2));
    ushort* W0a_bf = (ushort*)(ws + alloc((size_t)DH * DH * 2));
    ushort* W0b_bf = (ushort*)(ws + alloc((size_t)N0_P * DH * 2));
    ushort* W1a_bf = (ushort*)(ws + alloc((size_t)256 * DH * 2));
    ushort* W1b_bf = (ushort*)(ws + alloc((size_t)N1_P * 256 * 2));
    ushort* h0_bf  = (ushort*)(ws + alloc((size_t)BATCH * DH * 2));
    ushort* h1_bf  = (ushort*)(ws + alloc((size_t)BATCH * 256 * 2));
    float*  headL  = (float*)(ws + alloc((size_t)BATCH * OUT_HEAD * 4));
    float*  s01    = (float*)(ws + alloc((size_t)BATCH * 2 * 4));
    float*  rs0    = (float*)(ws + alloc((size_t)BATCH * 4));
    float*  rs1    = (float*)(ws + alloc((size_t)BATCH * 4));
    float*  add0   = (float*)(ws + alloc((size_t)BATCH * 4));
    float*  add1   = (float*)(ws + alloc((size_t)BATCH * 4));
    ushort* L0     = (ushort*)(ws + alloc((size_t)BATCH * N0_P * 2));

    convert_all_kernel<<<dim3(1280, 6), 256, 0, stream>>>(
        (const float4*)x,   (ushort4*)x_bf,   BATCH * DH / 4,        BATCH * DH / 4,
        (const float4*)Wh,  (ushort4*)Wh_bf,  OUT_HEAD * DH / 4,     NH_P * DH / 4,
        (const float4*)W0a, (ushort4*)W0a_bf, DH * DH / 4,           DH * DH / 4,
        (const float4*)W0b, (ushort4*)W0b_bf, (CC1 - CC0) * DH / 4,  N0_P * DH / 4,
        (const float4*)W1a, (ushort4*)W1a_bf, 256 * DH / 4,          256 * DH / 4,
        (const float4*)W1b, (ushort4*)W1b_bf, (CC2 - CC1) * 256 / 4, N1_P * 256 / 4);

    zero_kernel<<<(BATCH + 255) / 256, 256, 0, stream>>>(rs0, rs1, BATCH);

    // h0 = x @ W0a^T (bf16), h1 = x @ W1a^T (bf16)
    gemm128_kernel<1><<<dim3(DH / 128, BATCH / 128), 256, 0, stream>>>(
        x_bf, W0a_bf, h0_bf, BATCH, DH, DH, DH);
    gemm128_kernel<1><<<dim3(256 / 128, BATCH / 128), 256, 0, stream>>>(
        x_bf, W1a_bf, h1_bf, BATCH, 256, DH, 256);
    // head logits (fp32, ws)
    gemm128_kernel<2><<<dim3(NH_P / 128, BATCH / 128), 256, 0, stream>>>(
        x_bf, Wh_bf, headL, BATCH, OUT_HEAD, DH, OUT_HEAD);
    // head log-softmax -> out[:, :2000] + cluster scalars
    head_lsm_kernel<<<BATCH, 256, 0, stream>>>(headL, bh, out, s01);
    // tail0: bf16 logits (ws) + rowsum (256^2 8-phase)
    gemm256_kernel<1, true><<<dim3(N0_P / 256, BATCH / 256), 512, 0, stream>>>(
        h0_bf, W0b_bf, L0, BATCH, CC1 - CC0, DH, N0_P, rs0, nullptr);
    // tail1 pass1: rowsum only, no store
    gemm256_kernel<0, true><<<dim3(N1_P / 256, BATCH / 256), 512, 0, stream>>>(
        h1_bf, W1b_bf, nullptr, BATCH, CC2 - CC1, 256, 0, rs1, nullptr);
    // per-row additive constants
    prep_add_kernel<<<(BATCH + 255) / 256, 256, 0, stream>>>(s01, rs0, rs1, add0, add1, BATCH);
    // tail1 pass2: recompute, write normalized fp32 directly to out
    gemm256_kernel<3, false><<<dim3(N1_P / 256, BATCH / 256), 512, 0, stream>>>(
        h1_bf, W1b_bf, out + CC1, BATCH, CC2 - CC1, 256, CC2, nullptr, add1);
    // tail0: bf16 logits -> fp32 out with additive correction
    finalize_bf16_kernel<<<dim3((1000 + 255) / 256, BATCH), 256, 0, stream>>>(
        L0, N0_P, 1000, out + CC0, add0);
}

// Round 7
// 801.724 us; speedup vs baseline: 1.1877x; 1.0364x over previous
//
#include <hip/hip_runtime.h>
#include <hip/hip_bf16.h>
#include <math.h>

#define CC0 2000
#define CC1 10000
#define CC2 50000
#define DH  1024
#define BATCH 4096
#define OUT_HEAD (CC0 + 2)

typedef __attribute__((ext_vector_type(4))) float  f32x4;
typedef __attribute__((ext_vector_type(8))) __bf16 bf16x8;
typedef __attribute__((ext_vector_type(8))) short  s16x8;

__device__ __forceinline__ void gload_lds16(const void* g, void* l) {
    __builtin_amdgcn_global_load_lds(
        (const __attribute__((address_space(1))) void*)g,
        (__attribute__((address_space(3))) void*)l, 16, 0, 0);
}

// ---------------- all fp32 -> bf16 conversions in one launch (6 segments) ----------
__global__ __launch_bounds__(256) void convert_all_kernel(
    const float4* __restrict__ s0, ushort4* __restrict__ d0, int n0s, int n0d,
    const float4* __restrict__ s1, ushort4* __restrict__ d1, int n1s, int n1d,
    const float4* __restrict__ s2, ushort4* __restrict__ d2, int n2s, int n2d,
    const float4* __restrict__ s3, ushort4* __restrict__ d3, int n3s, int n3d,
    const float4* __restrict__ s4, ushort4* __restrict__ d4, int n4s, int n4d,
    const float4* __restrict__ s5, ushort4* __restrict__ d5, int n5s, int n5d)
{
    const float4* src; ushort4* dst; int ns, nd;
    switch (blockIdx.y) {
        case 0: src = s0; dst = d0; ns = n0s; nd = n0d; break;
        case 1: src = s1; dst = d1; ns = n1s; nd = n1d; break;
        case 2: src = s2; dst = d2; ns = n2s; nd = n2d; break;
        case 3: src = s3; dst = d3; ns = n3s; nd = n3d; break;
        case 4: src = s4; dst = d4; ns = n4s; nd = n4d; break;
        default: src = s5; dst = d5; ns = n5s; nd = n5d; break;
    }
    int i = blockIdx.x * blockDim.x + threadIdx.x;
    const int stride = gridDim.x * blockDim.x;
    for (; i < nd; i += stride) {
        ushort4 o = {0, 0, 0, 0};
        if (i < ns) {
            float4 v = src[i];
            o.x = __builtin_bit_cast(unsigned short, (__bf16)v.x);
            o.y = __builtin_bit_cast(unsigned short, (__bf16)v.y);
            o.z = __builtin_bit_cast(unsigned short, (__bf16)v.z);
            o.w = __builtin_bit_cast(unsigned short, (__bf16)v.w);
        }
        dst[i] = o;
    }
}

// ---------------- zero row-sum accumulators ----------------
__global__ __launch_bounds__(256) void zero_kernel(float* __restrict__ a,
                                                   float* __restrict__ b, int n) {
    int i = blockIdx.x * blockDim.x + threadIdx.x;
    if (i < n) { a[i] = 0.f; b[i] = 0.f; }
}

// ---------------- 128x128 MFMA GEMM (m97 structure) for small GEMMs --------------
// WMODE: 1 = bf16 C, 2 = f32 C
template <int WMODE>
__global__ __launch_bounds__(256) void gemm128_kernel(
    const ushort* __restrict__ A, const ushort* __restrict__ B,
    void* __restrict__ Cp, int M, int N, int K, int ldC)
{
    __shared__ ushort As[128 * 64];
    __shared__ ushort Bs[128 * 64];

    const int nwg = gridDim.x * gridDim.y;
    const int q = nwg >> 3;
    int bid = blockIdx.y * gridDim.x + blockIdx.x;
    bid = (bid & 7) * q + (bid >> 3);
    const int bx = bid % gridDim.x;
    const int by = bid / gridDim.x;

    const int t = threadIdx.x;
    const int lane = t & 63;
    const int w = t >> 6;
    const int wr = w >> 1, wc = w & 1;
    const int lr = lane & 15;
    const int lg = lane >> 4;
    const int bm = by * 128;
    const int bn = bx * 128;
    const int lrow = lane >> 3;
    const int lcol = (lane & 7) * 8;

    f32x4 acc[4][4] = {};

    for (int k0 = 0; k0 < K; k0 += 64) {
        #pragma unroll
        for (int i = 0; i < 4; ++i) {
            const int seg = w * 4 + i;
            const int row = seg * 8 + lrow;
            gload_lds16(A + (size_t)(bm + row) * K + k0 + lcol, &As[seg * 512]);
            gload_lds16(B + (size_t)(bn + row) * K + k0 + lcol, &Bs[seg * 512]);
        }
        __syncthreads();
        #pragma unroll
        for (int ks = 0; ks < 2; ++ks) {
            s16x8 af[4], bfr[4];
            #pragma unroll
            for (int m = 0; m < 4; ++m)
                af[m] = *(const s16x8*)&As[(wr * 64 + m * 16 + lr) * 64 + ks * 32 + lg * 8];
            #pragma unroll
            for (int n = 0; n < 4; ++n)
                bfr[n] = *(const s16x8*)&Bs[(wc * 64 + n * 16 + lr) * 64 + ks * 32 + lg * 8];
            #pragma unroll
            for (int m = 0; m < 4; ++m)
                #pragma unroll
                for (int n = 0; n < 4; ++n)
                    acc[m][n] = __builtin_amdgcn_mfma_f32_16x16x32_bf16(
                        __builtin_bit_cast(bf16x8, af[m]),
                        __builtin_bit_cast(bf16x8, bfr[n]), acc[m][n], 0, 0, 0);
        }
        __syncthreads();
    }

    #pragma unroll
    for (int m = 0; m < 4; ++m) {
        #pragma unroll
        for (int r = 0; r < 4; ++r) {
            const int row = bm + wr * 64 + m * 16 + lg * 4 + r;
            #pragma unroll
            for (int n = 0; n < 4; ++n) {
                const int col = bn + wc * 64 + n * 16 + lr;
                float v = acc[m][n][r];
                if (col < N) {
                    if (WMODE == 1)
                        ((ushort*)Cp)[(size_t)row * ldC + col] =
                            __builtin_bit_cast(unsigned short, (__bf16)v);
                    else
                        ((float*)Cp)[(size_t)row * ldC + col] = v;
                }
            }
        }
    }
}

// ---------------- 256x256 MFMA GEMM, 2-phase schedule (T3-minimum) ----------------
// WMODE: 0 = no C write, 1 = bf16 C, 3 = f32 C + addv[row]
// 8 waves (2Mx4N), 512 threads; wave = 128x64 out via 8x4 16x16x32 frags; BK=64.
// Per K-tile: issue ALL next-tile stage loads first (8 gload_lds/thread), then
// compute 4 quadrants with NO intra-tile barriers (read-only LDS), then one
// vmcnt(0)+barrier.  Issue-to-wait distance = full tile of MFMAs >> HBM latency.
// XOR swizzle byte^=((row&7)<<4): pre-swizzled global source + swizzled ds_read.
template <int WMODE, bool SUMEXP>
__global__ __launch_bounds__(512, 1) void gemm256_kernel(
    const ushort* __restrict__ A, const ushort* __restrict__ B,
    void* __restrict__ Cp, int M, int N, int K, int ldC,
    float* __restrict__ rowsum, const float* __restrict__ addv)
{
    __shared__ ushort lds[2][2][256 * 64];   // [buf][A/B] = 128 KiB total

    const int nwg = gridDim.x * gridDim.y;
    const int q8 = nwg >> 3;
    int bid = blockIdx.y * gridDim.x + blockIdx.x;
    bid = (bid & 7) * q8 + (bid >> 3);
    const int bx = bid % gridDim.x;
    const int by = bid / gridDim.x;
    const int bm = by * 256, bn = bx * 256;

    const int t = threadIdx.x;
    const int lane = t & 63;
    const int w = t >> 6;        // 0..7
    const int wr = w >> 2;       // 0..1  (M half)
    const int wc = w & 3;        // 0..3  (N quarter)
    const int lr = lane & 15;
    const int lg = lane >> 4;
    const int xr = (lr & 7) << 4;          // read-side XOR (bits 4-6)
    const int c0 = w * 64 + lane;          // staging chunk id (i=0)

    f32x4 acc[8][4] = {};
    const int nkt = K / 64;

    // stage one full K-tile (A+B, 4 halves x 2 chunks/thread) into buffer `buf`
    auto stage_tile = [&](int ktile, int buf) {
        const int k0 = ktile * 64;
        #pragma unroll
        for (int h = 0; h < 4; ++h) {
            const int r0 = (h >> 1) * 128;
            const int mat = h & 1;
            const ushort* gbase = mat ? B : A;
            const int brow = mat ? bn : bm;
            #pragma unroll
            for (int i = 0; i < 2; ++i) {
                const int c = i * 512 + c0;
                const int rl = c >> 3;
                const int cc = (c & 7) ^ (rl & 7);
                gload_lds16(gbase + (size_t)(brow + r0 + rl) * K + k0 + cc * 8,
                            (char*)&lds[buf][mat][0] + r0 * 128 + (i * 512 + w * 64) * 16);
            }
        }
    };

    // ---- prologue
    stage_tile(0, 0);
    asm volatile("s_waitcnt vmcnt(0)");
    __builtin_amdgcn_s_barrier();
    asm volatile("" ::: "memory");

    for (int tk = 0; tk < nkt; ++tk) {
        const int cur = tk & 1;
        if (tk + 1 < nkt) stage_tile(tk + 1, cur ^ 1);   // issue early, wait late
        const char* baseA = (const char*)&lds[cur][0][0];
        const char* baseB = (const char*)&lds[cur][1][0];
        #pragma unroll
        for (int q = 0; q < 4; ++q) {
            const int mh = q >> 1, nh = q & 1;
            s16x8 af[4][2], bf_[2][2];
            #pragma unroll
            for (int m_ = 0; m_ < 4; ++m_) {
                const int row = wr * 128 + (mh * 4 + m_) * 16 + lr;
                #pragma unroll
                for (int ks = 0; ks < 2; ++ks)
                    af[m_][ks] = *(const s16x8*)(baseA + (row * 128 + ((ks * 64 + lg * 16) ^ xr)));
            }
            #pragma unroll
            for (int n_ = 0; n_ < 2; ++n_) {
                const int row = wc * 64 + (nh * 2 + n_) * 16 + lr;
                #pragma unroll
                for (int ks = 0; ks < 2; ++ks)
                    bf_[n_][ks] = *(const s16x8*)(baseB + (row * 128 + ((ks * 64 + lg * 16) ^ xr)));
            }
            __builtin_amdgcn_s_setprio(1);
            #pragma unroll
            for (int m_ = 0; m_ < 4; ++m_)
                #pragma unroll
                for (int n_ = 0; n_ < 2; ++n_)
                    #pragma unroll
                    for (int ks = 0; ks < 2; ++ks)
                        acc[mh * 4 + m_][nh * 2 + n_] = __builtin_amdgcn_mfma_f32_16x16x32_bf16(
                            __builtin_bit_cast(bf16x8, af[m_][ks]),
                            __builtin_bit_cast(bf16x8, bf_[n_][ks]),
                            acc[mh * 4 + m_][nh * 2 + n_], 0, 0, 0);
            __builtin_amdgcn_s_setprio(0);
            __builtin_amdgcn_sched_barrier(0);   // bound register pressure per quadrant
        }
        asm volatile("s_waitcnt vmcnt(0)" ::: "memory");
        __builtin_amdgcn_s_barrier();
        asm volatile("" ::: "memory");
    }

    // ---- epilogue: row = bm + wr*128 + m*16 + lg*4 + r; col = bn + wc*64 + n*16 + lr
    #pragma unroll
    for (int m = 0; m < 8; ++m) {
        #pragma unroll
        for (int r = 0; r < 4; ++r) {
            const int row = bm + wr * 128 + m * 16 + lg * 4 + r;
            const float addr_ = (WMODE == 3) ? addv[row] : 0.f;
            float psum = 0.f;
            #pragma unroll
            for (int n = 0; n < 4; ++n) {
                const int col = bn + wc * 64 + n * 16 + lr;
                float v = acc[m][n][r];
                if (col < N) {
                    if (WMODE == 1)
                        ((ushort*)Cp)[(size_t)row * ldC + col] =
                            __builtin_bit_cast(unsigned short, (__bf16)v);
                    else if (WMODE == 3)
                        ((float*)Cp)[(size_t)row * ldC + col] = v + addr_;
                    if (SUMEXP) psum += __expf(v);   // logits O(1): max-free LSE safe
                }
            }
            if (SUMEXP) {
                #pragma unroll
                for (int mm = 1; mm < 16; mm <<= 1) psum += __shfl_xor(psum, mm, 64);
                if (lr == 0) atomicAdd(&rowsum[row], psum);
            }
        }
    }
}

// ---------------- head log-softmax: one block per row ----------------
__global__ __launch_bounds__(256) void head_lsm_kernel(
    const float* __restrict__ HL, const float* __restrict__ bh,
    float* __restrict__ out, float* __restrict__ s01)
{
    const int row = blockIdx.x;
    const float* L = HL + (size_t)row * OUT_HEAD;
    const int t = threadIdx.x;
    __shared__ float red[4];

    float m = -1e30f;
    for (int i = t; i < OUT_HEAD; i += 256) m = fmaxf(m, L[i] + bh[i]);
    #pragma unroll
    for (int s = 1; s < 64; s <<= 1) m = fmaxf(m, __shfl_xor(m, s, 64));
    if ((t & 63) == 0) red[t >> 6] = m;
    __syncthreads();
    m = fmaxf(fmaxf(red[0], red[1]), fmaxf(red[2], red[3]));

    float sum = 0.f;
    for (int i = t; i < OUT_HEAD; i += 256) sum += __expf(L[i] + bh[i] - m);
    #pragma unroll
    for (int s = 1; s < 64; s <<= 1) sum += __shfl_xor(sum, s, 64);
    __syncthreads();
    if ((t & 63) == 0) red[t >> 6] = sum;
    __syncthreads();
    const float lse = m + logf(red[0] + red[1] + red[2] + red[3]);

    float* orow = out + (size_t)row * CC2;
    for (int i = t; i < CC0; i += 256) orow[i] = L[i] + bh[i] - lse;
    if (t == 0) {
        s01[2 * row + 0] = L[CC0 + 0] + bh[CC0 + 0] - lse;
        s01[2 * row + 1] = L[CC0 + 1] + bh[CC0 + 1] - lse;
    }
}

// ---------------- per-row additive constants: add = s01 - log(rowsum) ----------------
__global__ __launch_bounds__(256) void prep_add_kernel(
    const float* __restrict__ s01, const float* __restrict__ rs0,
    const float* __restrict__ rs1, float* __restrict__ add0,
    float* __restrict__ add1, int n)
{
    int i = blockIdx.x * blockDim.x + threadIdx.x;
    if (i < n) {
        add0[i] = s01[2 * i + 0] - logf(rs0[i]);
        add1[i] = s01[2 * i + 1] - logf(rs1[i]);
    }
}

// ---------------- finalize tail0 from bf16 logits: out = bf16logit + add0[row] ----------
__global__ __launch_bounds__(256) void finalize_bf16_kernel(
    const ushort* __restrict__ Lg, int ldL, int ncols8,
    float* __restrict__ outb, const float* __restrict__ addv)
{
    const int row = blockIdx.y;
    const float add = addv[row];
    const int c = blockIdx.x * blockDim.x + threadIdx.x;
    if (c >= ncols8) return;
    s16x8 v = *(const s16x8*)(Lg + (size_t)row * ldL + c * 8);
    float* o = outb + (size_t)row * CC2 + c * 8;
    float4 o0, o1;
    o0.x = __builtin_bit_cast(float, (unsigned)(unsigned short)v[0] << 16) + add;
    o0.y = __builtin_bit_cast(float, (unsigned)(unsigned short)v[1] << 16) + add;
    o0.z = __builtin_bit_cast(float, (unsigned)(unsigned short)v[2] << 16) + add;
    o0.w = __builtin_bit_cast(float, (unsigned)(unsigned short)v[3] << 16) + add;
    o1.x = __builtin_bit_cast(float, (unsigned)(unsigned short)v[4] << 16) + add;
    o1.y = __builtin_bit_cast(float, (unsigned)(unsigned short)v[5] << 16) + add;
    o1.z = __builtin_bit_cast(float, (unsigned)(unsigned short)v[6] << 16) + add;
    o1.w = __builtin_bit_cast(float, (unsigned)(unsigned short)v[7] << 16) + add;
    *(float4*)o = o0;
    *(float4*)(o + 4) = o1;
}

// ---------------- launch ----------------
extern "C" void kernel_launch(void* const* d_in, const int* in_sizes, int n_in,
                              void* d_out, int out_size, void* d_ws, size_t ws_size,
                              hipStream_t stream) {
    const float* x   = (const float*)d_in[0];
    const float* Wh  = (const float*)d_in[1];
    const float* bh  = (const float*)d_in[2];
    const float* W0a = (const float*)d_in[3];
    const float* W0b = (const float*)d_in[4];
    const float* W1a = (const float*)d_in[5];
    const float* W1b = (const float*)d_in[6];
    float* out = (float*)d_out;
    char*  ws  = (char*)d_ws;

    // padded row counts
    const int NH_P  = 2048;    // head rows, mult of 128
    const int N0_P  = 8192;    // tail0 proj rows, mult of 256
    const int N1_P  = 40192;   // tail1 proj rows, mult of 256 (157 tiles)

    size_t off = 0;
    auto alloc = [&](size_t bytes) { size_t o = off; off += (bytes + 255) & ~(size_t)255; return o; };
    ushort* x_bf   = (ushort*)(ws + alloc((size_t)BATCH * DH * 2));
    ushort* Wh_bf  = (ushort*)(ws + alloc((size_t)NH_P * DH * 2));
    ushort* W0a_bf = (ushort*)(ws + alloc((size_t)DH * DH * 2));
    ushort* W0b_bf = (ushort*)(ws + alloc((size_t)N0_P * DH * 2));
    ushort* W1a_bf = (ushort*)(ws + alloc((size_t)256 * DH * 2));
    ushort* W1b_bf = (ushort*)(ws + alloc((size_t)N1_P * 256 * 2));
    ushort* h0_bf  = (ushort*)(ws + alloc((size_t)BATCH * DH * 2));
    ushort* h1_bf  = (ushort*)(ws + alloc((size_t)BATCH * 256 * 2));
    float*  headL  = (float*)(ws + alloc((size_t)BATCH * OUT_HEAD * 4));
    float*  s01    = (float*)(ws + alloc((size_t)BATCH * 2 * 4));
    float*  rs0    = (float*)(ws + alloc((size_t)BATCH * 4));
    float*  rs1    = (float*)(ws + alloc((size_t)BATCH * 4));
    float*  add0   = (float*)(ws + alloc((size_t)BATCH * 4));
    float*  add1   = (float*)(ws + alloc((size_t)BATCH * 4));
    ushort* L0     = (ushort*)(ws + alloc((size_t)BATCH * N0_P * 2));

    convert_all_kernel<<<dim3(1280, 6), 256, 0, stream>>>(
        (const float4*)x,   (ushort4*)x_bf,   BATCH * DH / 4,        BATCH * DH / 4,
        (const float4*)Wh,  (ushort4*)Wh_bf,  OUT_HEAD * DH / 4,     NH_P * DH / 4,
        (const float4*)W0a, (ushort4*)W0a_bf, DH * DH / 4,           DH * DH / 4,
        (const float4*)W0b, (ushort4*)W0b_bf, (CC1 - CC0) * DH / 4,  N0_P * DH / 4,
        (const float4*)W1a, (ushort4*)W1a_bf, 256 * DH / 4,          256 * DH / 4,
        (const float4*)W1b, (ushort4*)W1b_bf, (CC2 - CC1) * 256 / 4, N1_P * 256 / 4);

    zero_kernel<<<(BATCH + 255) / 256, 256, 0, stream>>>(rs0, rs1, BATCH);

    // h0 = x @ W0a^T (bf16), h1 = x @ W1a^T (bf16)
    gemm128_kernel<1><<<dim3(DH / 128, BATCH / 128), 256, 0, stream>>>(
        x_bf, W0a_bf, h0_bf, BATCH, DH, DH, DH);
    gemm128_kernel<1><<<dim3(256 / 128, BATCH / 128), 256, 0, stream>>>(
        x_bf, W1a_bf, h1_bf, BATCH, 256, DH, 256);
    // head logits (fp32, ws)
    gemm128_kernel<2><<<dim3(NH_P / 128, BATCH / 128), 256, 0, stream>>>(
        x_bf, Wh_bf, headL, BATCH, OUT_HEAD, DH, OUT_HEAD);
    // head log-softmax -> out[:, :2000] + cluster scalars
    head_lsm_kernel<<<BATCH, 256, 0, stream>>>(headL, bh, out, s01);
    // tail0: bf16 logits (ws) + rowsum
    gemm256_kernel<1, true><<<dim3(N0_P / 256, BATCH / 256), 512, 0, stream>>>(
        h0_bf, W0b_bf, L0, BATCH, CC1 - CC0, DH, N0_P, rs0, nullptr);
    // tail1 pass1: rowsum only, no store
    gemm256_kernel<0, true><<<dim3(N1_P / 256, BATCH / 256), 512, 0, stream>>>(
        h1_bf, W1b_bf, nullptr, BATCH, CC2 - CC1, 256, 0, rs1, nullptr);
    // per-row additive constants
    prep_add_kernel<<<(BATCH + 255) / 256, 256, 0, stream>>>(s01, rs0, rs1, add0, add1, BATCH);
    // tail1 pass2: recompute, write normalized fp32 directly to out
    gemm256_kernel<3, false><<<dim3(N1_P / 256, BATCH / 256), 512, 0, stream>>>(
        h1_bf, W1b_bf, out + CC1, BATCH, CC2 - CC1, 256, CC2, nullptr, add1);
    // tail0: bf16 logits -> fp32 out with additive correction
    finalize_bf16_kernel<<<dim3((1000 + 255) / 256, BATCH), 256, 0, stream>>>(
        L0, N0_P, 1000, out + CC0, add0);
}

// Round 8
// 763.776 us; speedup vs baseline: 1.2467x; 1.0497x over previous
//
#include <hip/hip_runtime.h>
#include <hip/hip_bf16.h>
#include <math.h>

#define CC0 2000
#define CC1 10000
#define CC2 50000
#define DH  1024
#define BATCH 4096
#define OUT_HEAD (CC0 + 2)

typedef __attribute__((ext_vector_type(4))) float  f32x4;
typedef __attribute__((ext_vector_type(8))) __bf16 bf16x8;
typedef __attribute__((ext_vector_type(8))) short  s16x8;

__device__ __forceinline__ void gload_lds16(const void* g, void* l) {
    __builtin_amdgcn_global_load_lds(
        (const __attribute__((address_space(1))) void*)g,
        (__attribute__((address_space(3))) void*)l, 16, 0, 0);
}

// ---------------- all fp32 -> bf16 conversions in one launch (6 segments) ----------
__global__ __launch_bounds__(256) void convert_all_kernel(
    const float4* __restrict__ s0, ushort4* __restrict__ d0, int n0s, int n0d,
    const float4* __restrict__ s1, ushort4* __restrict__ d1, int n1s, int n1d,
    const float4* __restrict__ s2, ushort4* __restrict__ d2, int n2s, int n2d,
    const float4* __restrict__ s3, ushort4* __restrict__ d3, int n3s, int n3d,
    const float4* __restrict__ s4, ushort4* __restrict__ d4, int n4s, int n4d,
    const float4* __restrict__ s5, ushort4* __restrict__ d5, int n5s, int n5d)
{
    const float4* src; ushort4* dst; int ns, nd;
    switch (blockIdx.y) {
        case 0: src = s0; dst = d0; ns = n0s; nd = n0d; break;
        case 1: src = s1; dst = d1; ns = n1s; nd = n1d; break;
        case 2: src = s2; dst = d2; ns = n2s; nd = n2d; break;
        case 3: src = s3; dst = d3; ns = n3s; nd = n3d; break;
        case 4: src = s4; dst = d4; ns = n4s; nd = n4d; break;
        default: src = s5; dst = d5; ns = n5s; nd = n5d; break;
    }
    int i = blockIdx.x * blockDim.x + threadIdx.x;
    const int stride = gridDim.x * blockDim.x;
    for (; i < nd; i += stride) {
        ushort4 o = {0, 0, 0, 0};
        if (i < ns) {
            float4 v = src[i];
            o.x = __builtin_bit_cast(unsigned short, (__bf16)v.x);
            o.y = __builtin_bit_cast(unsigned short, (__bf16)v.y);
            o.z = __builtin_bit_cast(unsigned short, (__bf16)v.z);
            o.w = __builtin_bit_cast(unsigned short, (__bf16)v.w);
        }
        dst[i] = o;
    }
}

// ---------------- zero row-sum accumulators ----------------
__global__ __launch_bounds__(256) void zero_kernel(float* __restrict__ a,
                                                   float* __restrict__ b, int n) {
    int i = blockIdx.x * blockDim.x + threadIdx.x;
    if (i < n) { a[i] = 0.f; b[i] = 0.f; }
}

// ---------------- 128x128 MFMA GEMM (m97 structure) for small GEMMs --------------
// WMODE: 1 = bf16 C, 2 = f32 C
template <int WMODE>
__global__ __launch_bounds__(256) void gemm128_kernel(
    const ushort* __restrict__ A, const ushort* __restrict__ B,
    void* __restrict__ Cp, int M, int N, int K, int ldC)
{
    __shared__ ushort As[128 * 64];
    __shared__ ushort Bs[128 * 64];

    const int nwg = gridDim.x * gridDim.y;
    const int q = nwg >> 3;
    int bid = blockIdx.y * gridDim.x + blockIdx.x;
    bid = (bid & 7) * q + (bid >> 3);
    const int bx = bid % gridDim.x;
    const int by = bid / gridDim.x;

    const int t = threadIdx.x;
    const int lane = t & 63;
    const int w = t >> 6;
    const int wr = w >> 1, wc = w & 1;
    const int lr = lane & 15;
    const int lg = lane >> 4;
    const int bm = by * 128;
    const int bn = bx * 128;
    const int lrow = lane >> 3;
    const int lcol = (lane & 7) * 8;

    f32x4 acc[4][4] = {};

    for (int k0 = 0; k0 < K; k0 += 64) {
        #pragma unroll
        for (int i = 0; i < 4; ++i) {
            const int seg = w * 4 + i;
            const int row = seg * 8 + lrow;
            gload_lds16(A + (size_t)(bm + row) * K + k0 + lcol, &As[seg * 512]);
            gload_lds16(B + (size_t)(bn + row) * K + k0 + lcol, &Bs[seg * 512]);
        }
        __syncthreads();
        #pragma unroll
        for (int ks = 0; ks < 2; ++ks) {
            s16x8 af[4], bfr[4];
            #pragma unroll
            for (int m = 0; m < 4; ++m)
                af[m] = *(const s16x8*)&As[(wr * 64 + m * 16 + lr) * 64 + ks * 32 + lg * 8];
            #pragma unroll
            for (int n = 0; n < 4; ++n)
                bfr[n] = *(const s16x8*)&Bs[(wc * 64 + n * 16 + lr) * 64 + ks * 32 + lg * 8];
            #pragma unroll
            for (int m = 0; m < 4; ++m)
                #pragma unroll
                for (int n = 0; n < 4; ++n)
                    acc[m][n] = __builtin_amdgcn_mfma_f32_16x16x32_bf16(
                        __builtin_bit_cast(bf16x8, af[m]),
                        __builtin_bit_cast(bf16x8, bfr[n]), acc[m][n], 0, 0, 0);
        }
        __syncthreads();
    }

    #pragma unroll
    for (int m = 0; m < 4; ++m) {
        #pragma unroll
        for (int r = 0; r < 4; ++r) {
            const int row = bm + wr * 64 + m * 16 + lg * 4 + r;
            #pragma unroll
            for (int n = 0; n < 4; ++n) {
                const int col = bn + wc * 64 + n * 16 + lr;
                float v = acc[m][n][r];
                if (col < N) {
                    if (WMODE == 1)
                        ((ushort*)Cp)[(size_t)row * ldC + col] =
                            __builtin_bit_cast(unsigned short, (__bf16)v);
                    else
                        ((float*)Cp)[(size_t)row * ldC + col] = v;
                }
            }
        }
    }
}

// ---------------- 256x256 MFMA GEMM, 2-phase, fragment-minimal ds_reads -----------
// WMODE: 0 = no C write, 1 = bf16 C, 3 = f32 C + addv[row]
// 8 waves (2Mx4N), 512 threads; wave = 128x64 out via 8x4 16x16x32 frags; BK=64.
// Per K-tile: issue ALL next-tile stage loads (8 gload_lds/thread), then read
// B frags once (8 ds_read_b128) and A frags once per M-half (8+8), 64 MFMA,
// then ONE vmcnt(0)+barrier.  24 ds_reads / 64 MFMA = minimal fragment traffic.
// XOR swizzle byte^=((row&7)<<4): pre-swizzled global source + swizzled ds_read.
template <int WMODE, bool SUMEXP>
__global__ __launch_bounds__(512, 1) void gemm256_kernel(
    const ushort* __restrict__ A, const ushort* __restrict__ B,
    void* __restrict__ Cp, int M, int N, int K, int ldC,
    float* __restrict__ rowsum, const float* __restrict__ addv)
{
    __shared__ ushort lds[2][2][256 * 64];   // [buf][A/B] = 128 KiB total

    const int nwg = gridDim.x * gridDim.y;
    const int q8 = nwg >> 3;
    int bid = blockIdx.y * gridDim.x + blockIdx.x;
    bid = (bid & 7) * q8 + (bid >> 3);
    const int bx = bid % gridDim.x;
    const int by = bid / gridDim.x;
    const int bm = by * 256, bn = bx * 256;

    const int t = threadIdx.x;
    const int lane = t & 63;
    const int w = t >> 6;        // 0..7
    const int wr = w >> 2;       // 0..1  (M half)
    const int wc = w & 3;        // 0..3  (N quarter)
    const int lr = lane & 15;
    const int lg = lane >> 4;
    const int xr = (lr & 7) << 4;          // read-side XOR (bits 4-6)
    const int c0 = w * 64 + lane;          // staging chunk id (i=0)

    f32x4 acc[8][4] = {};
    const int nkt = K / 64;

    // stage one full K-tile (A+B, 4 halves x 2 chunks/thread) into buffer `buf`
    auto stage_tile = [&](int ktile, int buf) {
        const int k0 = ktile * 64;
        #pragma unroll
        for (int h = 0; h < 4; ++h) {
            const int r0 = (h >> 1) * 128;
            const int mat = h & 1;
            const ushort* gbase = mat ? B : A;
            const int brow = mat ? bn : bm;
            #pragma unroll
            for (int i = 0; i < 2; ++i) {
                const int c = i * 512 + c0;
                const int rl = c >> 3;
                const int cc = (c & 7) ^ (rl & 7);
                gload_lds16(gbase + (size_t)(brow + r0 + rl) * K + k0 + cc * 8,
                            (char*)&lds[buf][mat][0] + r0 * 128 + (i * 512 + w * 64) * 16);
            }
        }
    };

    // ---- prologue
    stage_tile(0, 0);
    asm volatile("s_waitcnt vmcnt(0)");
    __builtin_amdgcn_s_barrier();
    asm volatile("" ::: "memory");

    for (int tk = 0; tk < nkt; ++tk) {
        const int cur = tk & 1;
        if (tk + 1 < nkt) stage_tile(tk + 1, cur ^ 1);   // issue early, wait late
        const char* baseA = (const char*)&lds[cur][0][0];
        const char* baseB = (const char*)&lds[cur][1][0];

        // B fragments: read once per K-tile (8 ds_read_b128)
        s16x8 bfr[4][2];
        #pragma unroll
        for (int n_ = 0; n_ < 4; ++n_) {
            const int row = wc * 64 + n_ * 16 + lr;
            #pragma unroll
            for (int ks = 0; ks < 2; ++ks)
                bfr[n_][ks] = *(const s16x8*)(baseB + (row * 128 + ((ks * 64 + lg * 16) ^ xr)));
        }
        // A fragments: once per M-half; 32 MFMA per half
        #pragma unroll
        for (int mh = 0; mh < 2; ++mh) {
            s16x8 af[4][2];
            #pragma unroll
            for (int m_ = 0; m_ < 4; ++m_) {
                const int row = wr * 128 + (mh * 4 + m_) * 16 + lr;
                #pragma unroll
                for (int ks = 0; ks < 2; ++ks)
                    af[m_][ks] = *(const s16x8*)(baseA + (row * 128 + ((ks * 64 + lg * 16) ^ xr)));
            }
            __builtin_amdgcn_s_setprio(1);
            #pragma unroll
            for (int m_ = 0; m_ < 4; ++m_)
                #pragma unroll
                for (int n_ = 0; n_ < 4; ++n_)
                    #pragma unroll
                    for (int ks = 0; ks < 2; ++ks)
                        acc[mh * 4 + m_][n_] = __builtin_amdgcn_mfma_f32_16x16x32_bf16(
                            __builtin_bit_cast(bf16x8, af[m_][ks]),
                            __builtin_bit_cast(bf16x8, bfr[n_][ks]),
                            acc[mh * 4 + m_][n_], 0, 0, 0);
            __builtin_amdgcn_s_setprio(0);
        }
        asm volatile("s_waitcnt vmcnt(0)" ::: "memory");
        __builtin_amdgcn_s_barrier();
        asm volatile("" ::: "memory");
    }

    // ---- epilogue: row = bm + wr*128 + m*16 + lg*4 + r; col = bn + wc*64 + n*16 + lr
    #pragma unroll
    for (int m = 0; m < 8; ++m) {
        #pragma unroll
        for (int r = 0; r < 4; ++r) {
            const int row = bm + wr * 128 + m * 16 + lg * 4 + r;
            const float addr_ = (WMODE == 3) ? addv[row] : 0.f;
            float psum = 0.f;
            #pragma unroll
            for (int n = 0; n < 4; ++n) {
                const int col = bn + wc * 64 + n * 16 + lr;
                float v = acc[m][n][r];
                if (col < N) {
                    if (WMODE == 1)
                        ((ushort*)Cp)[(size_t)row * ldC + col] =
                            __builtin_bit_cast(unsigned short, (__bf16)v);
                    else if (WMODE == 3)
                        ((float*)Cp)[(size_t)row * ldC + col] = v + addr_;
                    if (SUMEXP) psum += __expf(v);   // logits O(1): max-free LSE safe
                }
            }
            if (SUMEXP) {
                #pragma unroll
                for (int mm = 1; mm < 16; mm <<= 1) psum += __shfl_xor(psum, mm, 64);
                if (lr == 0) atomicAdd(&rowsum[row], psum);
            }
        }
    }
}

// ---------------- head log-softmax: one block per row ----------------
__global__ __launch_bounds__(256) void head_lsm_kernel(
    const float* __restrict__ HL, const float* __restrict__ bh,
    float* __restrict__ out, float* __restrict__ s01)
{
    const int row = blockIdx.x;
    const float* L = HL + (size_t)row * OUT_HEAD;
    const int t = threadIdx.x;
    __shared__ float red[4];

    float m = -1e30f;
    for (int i = t; i < OUT_HEAD; i += 256) m = fmaxf(m, L[i] + bh[i]);
    #pragma unroll
    for (int s = 1; s < 64; s <<= 1) m = fmaxf(m, __shfl_xor(m, s, 64));
    if ((t & 63) == 0) red[t >> 6] = m;
    __syncthreads();
    m = fmaxf(fmaxf(red[0], red[1]), fmaxf(red[2], red[3]));

    float sum = 0.f;
    for (int i = t; i < OUT_HEAD; i += 256) sum += __expf(L[i] + bh[i] - m);
    #pragma unroll
    for (int s = 1; s < 64; s <<= 1) sum += __shfl_xor(sum, s, 64);
    __syncthreads();
    if ((t & 63) == 0) red[t >> 6] = sum;
    __syncthreads();
    const float lse = m + logf(red[0] + red[1] + red[2] + red[3]);

    float* orow = out + (size_t)row * CC2;
    for (int i = t; i < CC0; i += 256) orow[i] = L[i] + bh[i] - lse;
    if (t == 0) {
        s01[2 * row + 0] = L[CC0 + 0] + bh[CC0 + 0] - lse;
        s01[2 * row + 1] = L[CC0 + 1] + bh[CC0 + 1] - lse;
    }
}

// ---------------- per-row additive constants: add = s01 - log(rowsum) ----------------
__global__ __launch_bounds__(256) void prep_add_kernel(
    const float* __restrict__ s01, const float* __restrict__ rs0,
    const float* __restrict__ rs1, float* __restrict__ add0,
    float* __restrict__ add1, int n)
{
    int i = blockIdx.x * blockDim.x + threadIdx.x;
    if (i < n) {
        add0[i] = s01[2 * i + 0] - logf(rs0[i]);
        add1[i] = s01[2 * i + 1] - logf(rs1[i]);
    }
}

// ---------------- finalize tail0 from bf16 logits: out = bf16logit + add0[row] ----------
__global__ __launch_bounds__(256) void finalize_bf16_kernel(
    const ushort* __restrict__ Lg, int ldL, int ncols8,
    float* __restrict__ outb, const float* __restrict__ addv)
{
    const int row = blockIdx.y;
    const float add = addv[row];
    const int c = blockIdx.x * blockDim.x + threadIdx.x;
    if (c >= ncols8) return;
    s16x8 v = *(const s16x8*)(Lg + (size_t)row * ldL + c * 8);
    float* o = outb + (size_t)row * CC2 + c * 8;
    float4 o0, o1;
    o0.x = __builtin_bit_cast(float, (unsigned)(unsigned short)v[0] << 16) + add;
    o0.y = __builtin_bit_cast(float, (unsigned)(unsigned short)v[1] << 16) + add;
    o0.z = __builtin_bit_cast(float, (unsigned)(unsigned short)v[2] << 16) + add;
    o0.w = __builtin_bit_cast(float, (unsigned)(unsigned short)v[3] << 16) + add;
    o1.x = __builtin_bit_cast(float, (unsigned)(unsigned short)v[4] << 16) + add;
    o1.y = __builtin_bit_cast(float, (unsigned)(unsigned short)v[5] << 16) + add;
    o1.z = __builtin_bit_cast(float, (unsigned)(unsigned short)v[6] << 16) + add;
    o1.w = __builtin_bit_cast(float, (unsigned)(unsigned short)v[7] << 16) + add;
    *(float4*)o = o0;
    *(float4*)(o + 4) = o1;
}

// ---------------- launch ----------------
extern "C" void kernel_launch(void* const* d_in, const int* in_sizes, int n_in,
                              void* d_out, int out_size, void* d_ws, size_t ws_size,
                              hipStream_t stream) {
    const float* x   = (const float*)d_in[0];
    const float* Wh  = (const float*)d_in[1];
    const float* bh  = (const float*)d_in[2];
    const float* W0a = (const float*)d_in[3];
    const float* W0b = (const float*)d_in[4];
    const float* W1a = (const float*)d_in[5];
    const float* W1b = (const float*)d_in[6];
    float* out = (float*)d_out;
    char*  ws  = (char*)d_ws;

    // padded row counts
    const int NH_P  = 2048;    // head rows, mult of 128
    const int N0_P  = 8192;    // tail0 proj rows, mult of 256
    const int N1_P  = 40192;   // tail1 proj rows, mult of 256 (157 tiles)

    size_t off = 0;
    auto alloc = [&](size_t bytes) { size_t o = off; off += (bytes + 255) & ~(size_t)255; return o; };
    ushort* x_bf   = (ushort*)(ws + alloc((size_t)BATCH * DH * 2));
    ushort* Wh_bf  = (ushort*)(ws + alloc((size_t)NH_P * DH * 2));
    ushort* W0a_bf = (ushort*)(ws + alloc((size_t)DH * DH * 2));
    ushort* W0b_bf = (ushort*)(ws + alloc((size_t)N0_P * DH * 2));
    ushort* W1a_bf = (ushort*)(ws + alloc((size_t)256 * DH * 2));
    ushort* W1b_bf = (ushort*)(ws + alloc((size_t)N1_P * 256 * 2));
    ushort* h0_bf  = (ushort*)(ws + alloc((size_t)BATCH * DH * 2));
    ushort* h1_bf  = (ushort*)(ws + alloc((size_t)BATCH * 256 * 2));
    float*  headL  = (float*)(ws + alloc((size_t)BATCH * OUT_HEAD * 4));
    float*  s01    = (float*)(ws + alloc((size_t)BATCH * 2 * 4));
    float*  rs0    = (float*)(ws + alloc((size_t)BATCH * 4));
    float*  rs1    = (float*)(ws + alloc((size_t)BATCH * 4));
    float*  add0   = (float*)(ws + alloc((size_t)BATCH * 4));
    float*  add1   = (float*)(ws + alloc((size_t)BATCH * 4));
    ushort* L0     = (ushort*)(ws + alloc((size_t)BATCH * N0_P * 2));

    convert_all_kernel<<<dim3(1280, 6), 256, 0, stream>>>(
        (const float4*)x,   (ushort4*)x_bf,   BATCH * DH / 4,        BATCH * DH / 4,
        (const float4*)Wh,  (ushort4*)Wh_bf,  OUT_HEAD * DH / 4,     NH_P * DH / 4,
        (const float4*)W0a, (ushort4*)W0a_bf, DH * DH / 4,           DH * DH / 4,
        (const float4*)W0b, (ushort4*)W0b_bf, (CC1 - CC0) * DH / 4,  N0_P * DH / 4,
        (const float4*)W1a, (ushort4*)W1a_bf, 256 * DH / 4,          256 * DH / 4,
        (const float4*)W1b, (ushort4*)W1b_bf, (CC2 - CC1) * 256 / 4, N1_P * 256 / 4);

    zero_kernel<<<(BATCH + 255) / 256, 256, 0, stream>>>(rs0, rs1, BATCH);

    // h0 = x @ W0a^T (bf16), h1 = x @ W1a^T (bf16)
    gemm128_kernel<1><<<dim3(DH / 128, BATCH / 128), 256, 0, stream>>>(
        x_bf, W0a_bf, h0_bf, BATCH, DH, DH, DH);
    gemm128_kernel<1><<<dim3(256 / 128, BATCH / 128), 256, 0, stream>>>(
        x_bf, W1a_bf, h1_bf, BATCH, 256, DH, 256);
    // head logits (fp32, ws)
    gemm128_kernel<2><<<dim3(NH_P / 128, BATCH / 128), 256, 0, stream>>>(
        x_bf, Wh_bf, headL, BATCH, OUT_HEAD, DH, OUT_HEAD);
    // head log-softmax -> out[:, :2000] + cluster scalars
    head_lsm_kernel<<<BATCH, 256, 0, stream>>>(headL, bh, out, s01);
    // tail0: bf16 logits (ws) + rowsum
    gemm256_kernel<1, true><<<dim3(N0_P / 256, BATCH / 256), 512, 0, stream>>>(
        h0_bf, W0b_bf, L0, BATCH, CC1 - CC0, DH, N0_P, rs0, nullptr);
    // tail1 pass1: rowsum only, no store
    gemm256_kernel<0, true><<<dim3(N1_P / 256, BATCH / 256), 512, 0, stream>>>(
        h1_bf, W1b_bf, nullptr, BATCH, CC2 - CC1, 256, 0, rs1, nullptr);
    // per-row additive constants
    prep_add_kernel<<<(BATCH + 255) / 256, 256, 0, stream>>>(s01, rs0, rs1, add0, add1, BATCH);
    // tail1 pass2: recompute, write normalized fp32 directly to out
    gemm256_kernel<3, false><<<dim3(N1_P / 256, BATCH / 256), 512, 0, stream>>>(
        h1_bf, W1b_bf, out + CC1, BATCH, CC2 - CC1, 256, CC2, nullptr, add1);
    // tail0: bf16 logits -> fp32 out with additive correction
    finalize_bf16_kernel<<<dim3((1000 + 255) / 256, BATCH), 256, 0, stream>>>(
        L0, N0_P, 1000, out + CC0, add0);
}

// Round 9
// 643.812 us; speedup vs baseline: 1.4790x; 1.1863x over previous
//
#include <hip/hip_runtime.h>
#include <hip/hip_bf16.h>
#include <math.h>

#define CC0 2000
#define CC1 10000
#define CC2 50000
#define DH  1024
#define BATCH 4096
#define OUT_HEAD (CC0 + 2)

typedef __attribute__((ext_vector_type(4))) float  f32x4;
typedef __attribute__((ext_vector_type(8))) __bf16 bf16x8;
typedef __attribute__((ext_vector_type(8))) short  s16x8;

__device__ __forceinline__ void gload_lds16(const void* g, void* l) {
    __builtin_amdgcn_global_load_lds(
        (const __attribute__((address_space(1))) void*)g,
        (__attribute__((address_space(3))) void*)l, 16, 0, 0);
}

// ------- fp32 -> bf16 conversions (6 segments) + rowsum zeroing (segment 6) -------
__global__ __launch_bounds__(256) void convert_all_kernel(
    const float4* __restrict__ s0, ushort4* __restrict__ d0, int n0s, int n0d,
    const float4* __restrict__ s1, ushort4* __restrict__ d1, int n1s, int n1d,
    const float4* __restrict__ s2, ushort4* __restrict__ d2, int n2s, int n2d,
    const float4* __restrict__ s3, ushort4* __restrict__ d3, int n3s, int n3d,
    const float4* __restrict__ s4, ushort4* __restrict__ d4, int n4s, int n4d,
    const float4* __restrict__ s5, ushort4* __restrict__ d5, int n5s, int n5d,
    float* __restrict__ rs0, float* __restrict__ rs1)
{
    if (blockIdx.y == 6) {
        int i = blockIdx.x * blockDim.x + threadIdx.x;
        if (i < BATCH) { rs0[i] = 0.f; rs1[i] = 0.f; }
        return;
    }
    const float4* src; ushort4* dst; int ns, nd;
    switch (blockIdx.y) {
        case 0: src = s0; dst = d0; ns = n0s; nd = n0d; break;
        case 1: src = s1; dst = d1; ns = n1s; nd = n1d; break;
        case 2: src = s2; dst = d2; ns = n2s; nd = n2d; break;
        case 3: src = s3; dst = d3; ns = n3s; nd = n3d; break;
        case 4: src = s4; dst = d4; ns = n4s; nd = n4d; break;
        default: src = s5; dst = d5; ns = n5s; nd = n5d; break;
    }
    int i = blockIdx.x * blockDim.x + threadIdx.x;
    const int stride = gridDim.x * blockDim.x;
    for (; i < nd; i += stride) {
        ushort4 o = {0, 0, 0, 0};
        if (i < ns) {
            float4 v = src[i];
            o.x = __builtin_bit_cast(unsigned short, (__bf16)v.x);
            o.y = __builtin_bit_cast(unsigned short, (__bf16)v.y);
            o.z = __builtin_bit_cast(unsigned short, (__bf16)v.z);
            o.w = __builtin_bit_cast(unsigned short, (__bf16)v.w);
        }
        dst[i] = o;
    }
}

// ------- fused small GEMMs: h0 = x@W0a^T (bf16), h1 = x@W1a^T (bf16), headL = x@Wh^T (f32)
// 128x128 tile (m97 structure), 4 waves, segment dispatch over blockIdx.x.
__global__ __launch_bounds__(256) void gemm128x3_kernel(
    const ushort* __restrict__ x_bf,
    const ushort* __restrict__ W0a_bf, ushort* __restrict__ h0,
    const ushort* __restrict__ W1a_bf, ushort* __restrict__ h1,
    const ushort* __restrict__ Wh_bf,  float*  __restrict__ headL)
{
    __shared__ ushort As[128 * 64];
    __shared__ ushort Bs[128 * 64];

    const int gb = blockIdx.x;
    const ushort* A = x_bf; const ushort* B; void* C;
    int N, ldC, wmode, nbx, lin;
    const int K = DH;
    if (gb < 256)      { B = W0a_bf; C = h0;    N = DH;       ldC = DH;       wmode = 1; nbx = 8;  lin = gb; }
    else if (gb < 320) { B = W1a_bf; C = h1;    N = 256;      ldC = 256;      wmode = 1; nbx = 2;  lin = gb - 256; }
    else               { B = Wh_bf;  C = headL; N = OUT_HEAD; ldC = OUT_HEAD; wmode = 2; nbx = 16; lin = gb - 320; }

    const int nwg = nbx * 32;
    const int q = nwg >> 3;
    int bid = (lin & 7) * q + (lin >> 3);
    const int bx = bid % nbx;      // by-major: A-row reuse within XCD chunk
    const int by = bid / nbx;

    const int t = threadIdx.x;
    const int lane = t & 63;
    const int w = t >> 6;
    const int wr = w >> 1, wc = w & 1;
    const int lr = lane & 15;
    const int lg = lane >> 4;
    const int bm = by * 128;
    const int bn = bx * 128;
    const int lrow = lane >> 3;
    const int lcol = (lane & 7) * 8;

    f32x4 acc[4][4] = {};

    for (int k0 = 0; k0 < K; k0 += 64) {
        #pragma unroll
        for (int i = 0; i < 4; ++i) {
            const int seg = w * 4 + i;
            const int row = seg * 8 + lrow;
            gload_lds16(A + (size_t)(bm + row) * K + k0 + lcol, &As[seg * 512]);
            gload_lds16(B + (size_t)(bn + row) * K + k0 + lcol, &Bs[seg * 512]);
        }
        __syncthreads();
        #pragma unroll
        for (int ks = 0; ks < 2; ++ks) {
            s16x8 af[4], bfr[4];
            #pragma unroll
            for (int m = 0; m < 4; ++m)
                af[m] = *(const s16x8*)&As[(wr * 64 + m * 16 + lr) * 64 + ks * 32 + lg * 8];
            #pragma unroll
            for (int n = 0; n < 4; ++n)
                bfr[n] = *(const s16x8*)&Bs[(wc * 64 + n * 16 + lr) * 64 + ks * 32 + lg * 8];
            #pragma unroll
            for (int m = 0; m < 4; ++m)
                #pragma unroll
                for (int n = 0; n < 4; ++n)
                    acc[m][n] = __builtin_amdgcn_mfma_f32_16x16x32_bf16(
                        __builtin_bit_cast(bf16x8, af[m]),
                        __builtin_bit_cast(bf16x8, bfr[n]), acc[m][n], 0, 0, 0);
        }
        __syncthreads();
    }

    #pragma unroll
    for (int m = 0; m < 4; ++m) {
        #pragma unroll
        for (int r = 0; r < 4; ++r) {
            const int row = bm + wr * 64 + m * 16 + lg * 4 + r;
            #pragma unroll
            for (int n = 0; n < 4; ++n) {
                const int col = bn + wc * 64 + n * 16 + lr;
                float v = acc[m][n][r];
                if (col < N) {
                    if (wmode == 1)
                        ((ushort*)C)[(size_t)row * ldC + col] =
                            __builtin_bit_cast(unsigned short, (__bf16)v);
                    else
                        ((float*)C)[(size_t)row * ldC + col] = v;
                }
            }
        }
    }
}

// ---------------- 256x256 MFMA GEMM, 2-phase, fragment-minimal ds_reads -----------
// WMODE: 0 = no C write, 1 = bf16 C, 3 = f32 C + addv[row]
// Panel-major work decode: consecutive works on an XCD share the B panel (bx),
// so B streams through L2 once per XCD; A (batch tile) is small and L2-resident.
template <int WMODE, bool SUMEXP>
__global__ __launch_bounds__(512, 1) void gemm256_kernel(
    const ushort* __restrict__ A, const ushort* __restrict__ B,
    void* __restrict__ Cp, int M, int N, int K, int ldC,
    float* __restrict__ rowsum, const float* __restrict__ addv)
{
    __shared__ ushort lds[2][2][256 * 64];   // [buf][A/B] = 128 KiB total

    const int nby = gridDim.y;
    const int nwg = gridDim.x * gridDim.y;
    const int q8 = nwg >> 3;
    int bid = blockIdx.y * gridDim.x + blockIdx.x;
    bid = (bid & 7) * q8 + (bid >> 3);
    const int by = bid % nby;      // panel-major: B-panel reuse within XCD chunk
    const int bx = bid / nby;
    const int bm = by * 256, bn = bx * 256;

    const int t = threadIdx.x;
    const int lane = t & 63;
    const int w = t >> 6;        // 0..7
    const int wr = w >> 2;       // 0..1  (M half)
    const int wc = w & 3;        // 0..3  (N quarter)
    const int lr = lane & 15;
    const int lg = lane >> 4;
    const int xr = (lr & 7) << 4;          // read-side XOR (bits 4-6)
    const int c0 = w * 64 + lane;          // staging chunk id (i=0)

    f32x4 acc[8][4] = {};
    const int nkt = K / 64;

    auto stage_tile = [&](int ktile, int buf) {
        const int k0 = ktile * 64;
        #pragma unroll
        for (int h = 0; h < 4; ++h) {
            const int r0 = (h >> 1) * 128;
            const int mat = h & 1;
            const ushort* gbase = mat ? B : A;
            const int brow = mat ? bn : bm;
            #pragma unroll
            for (int i = 0; i < 2; ++i) {
                const int c = i * 512 + c0;
                const int rl = c >> 3;
                const int cc = (c & 7) ^ (rl & 7);
                gload_lds16(gbase + (size_t)(brow + r0 + rl) * K + k0 + cc * 8,
                            (char*)&lds[buf][mat][0] + r0 * 128 + (i * 512 + w * 64) * 16);
            }
        }
    };

    // ---- prologue
    stage_tile(0, 0);
    asm volatile("s_waitcnt vmcnt(0)");
    __builtin_amdgcn_s_barrier();
    asm volatile("" ::: "memory");

    for (int tk = 0; tk < nkt; ++tk) {
        const int cur = tk & 1;
        if (tk + 1 < nkt) stage_tile(tk + 1, cur ^ 1);   // issue early, wait late
        const char* baseA = (const char*)&lds[cur][0][0];
        const char* baseB = (const char*)&lds[cur][1][0];

        // B fragments: read once per K-tile (8 ds_read_b128)
        s16x8 bfr[4][2];
        #pragma unroll
        for (int n_ = 0; n_ < 4; ++n_) {
            const int row = wc * 64 + n_ * 16 + lr;
            #pragma unroll
            for (int ks = 0; ks < 2; ++ks)
                bfr[n_][ks] = *(const s16x8*)(baseB + (row * 128 + ((ks * 64 + lg * 16) ^ xr)));
        }
        // A fragments: once per M-half; 32 MFMA per half
        #pragma unroll
        for (int mh = 0; mh < 2; ++mh) {
            s16x8 af[4][2];
            #pragma unroll
            for (int m_ = 0; m_ < 4; ++m_) {
                const int row = wr * 128 + (mh * 4 + m_) * 16 + lr;
                #pragma unroll
                for (int ks = 0; ks < 2; ++ks)
                    af[m_][ks] = *(const s16x8*)(baseA + (row * 128 + ((ks * 64 + lg * 16) ^ xr)));
            }
            __builtin_amdgcn_s_setprio(1);
            #pragma unroll
            for (int m_ = 0; m_ < 4; ++m_)
                #pragma unroll
                for (int n_ = 0; n_ < 4; ++n_)
                    #pragma unroll
                    for (int ks = 0; ks < 2; ++ks)
                        acc[mh * 4 + m_][n_] = __builtin_amdgcn_mfma_f32_16x16x32_bf16(
                            __builtin_bit_cast(bf16x8, af[m_][ks]),
                            __builtin_bit_cast(bf16x8, bfr[n_][ks]),
                            acc[mh * 4 + m_][n_], 0, 0, 0);
            __builtin_amdgcn_s_setprio(0);
        }
        asm volatile("s_waitcnt vmcnt(0)" ::: "memory");
        __builtin_amdgcn_s_barrier();
        asm volatile("" ::: "memory");
    }

    // ---- epilogue: row = bm + wr*128 + m*16 + lg*4 + r; col = bn + wc*64 + n*16 + lr
    #pragma unroll
    for (int m = 0; m < 8; ++m) {
        #pragma unroll
        for (int r = 0; r < 4; ++r) {
            const int row = bm + wr * 128 + m * 16 + lg * 4 + r;
            const float addr_ = (WMODE == 3) ? addv[row] : 0.f;
            float psum = 0.f;
            #pragma unroll
            for (int n = 0; n < 4; ++n) {
                const int col = bn + wc * 64 + n * 16 + lr;
                float v = acc[m][n][r];
                if (col < N) {
                    if (WMODE == 1)
                        ((ushort*)Cp)[(size_t)row * ldC + col] =
                            __builtin_bit_cast(unsigned short, (__bf16)v);
                    else if (WMODE == 3)
                        ((float*)Cp)[(size_t)row * ldC + col] = v + addr_;
                    if (SUMEXP) psum += __expf(v);   // logits O(1): max-free LSE safe
                }
            }
            if (SUMEXP) {
                #pragma unroll
                for (int mm = 1; mm < 16; mm <<= 1) psum += __shfl_xor(psum, mm, 64);
                if (lr == 0) atomicAdd(&rowsum[row], psum);
            }
        }
    }
}

// ---------------- head log-softmax: one block per row ----------------
__global__ __launch_bounds__(256) void head_lsm_kernel(
    const float* __restrict__ HL, const float* __restrict__ bh,
    float* __restrict__ out, float* __restrict__ s01)
{
    const int row = blockIdx.x;
    const float* L = HL + (size_t)row * OUT_HEAD;
    const int t = threadIdx.x;
    __shared__ float red[4];

    float m = -1e30f;
    for (int i = t; i < OUT_HEAD; i += 256) m = fmaxf(m, L[i] + bh[i]);
    #pragma unroll
    for (int s = 1; s < 64; s <<= 1) m = fmaxf(m, __shfl_xor(m, s, 64));
    if ((t & 63) == 0) red[t >> 6] = m;
    __syncthreads();
    m = fmaxf(fmaxf(red[0], red[1]), fmaxf(red[2], red[3]));

    float sum = 0.f;
    for (int i = t; i < OUT_HEAD; i += 256) sum += __expf(L[i] + bh[i] - m);
    #pragma unroll
    for (int s = 1; s < 64; s <<= 1) sum += __shfl_xor(sum, s, 64);
    __syncthreads();
    if ((t & 63) == 0) red[t >> 6] = sum;
    __syncthreads();
    const float lse = m + logf(red[0] + red[1] + red[2] + red[3]);

    float* orow = out + (size_t)row * CC2;
    for (int i = t; i < CC0; i += 256) orow[i] = L[i] + bh[i] - lse;
    if (t == 0) {
        s01[2 * row + 0] = L[CC0 + 0] + bh[CC0 + 0] - lse;
        s01[2 * row + 1] = L[CC0 + 1] + bh[CC0 + 1] - lse;
    }
}

// ---------------- per-row additive constants: add = s01 - log(rowsum) ----------------
__global__ __launch_bounds__(256) void prep_add_kernel(
    const float* __restrict__ s01, const float* __restrict__ rs0,
    const float* __restrict__ rs1, float* __restrict__ add0,
    float* __restrict__ add1, int n)
{
    int i = blockIdx.x * blockDim.x + threadIdx.x;
    if (i < n) {
        add0[i] = s01[2 * i + 0] - logf(rs0[i]);
        add1[i] = s01[2 * i + 1] - logf(rs1[i]);
    }
}

// ---------------- finalize tail0 from bf16 logits: out = bf16logit + add0[row] ----------
__global__ __launch_bounds__(256) void finalize_bf16_kernel(
    const ushort* __restrict__ Lg, int ldL, int ncols8,
    float* __restrict__ outb, const float* __restrict__ addv)
{
    const int row = blockIdx.y;
    const float add = addv[row];
    const int c = blockIdx.x * blockDim.x + threadIdx.x;
    if (c >= ncols8) return;
    s16x8 v = *(const s16x8*)(Lg + (size_t)row * ldL + c * 8);
    float* o = outb + (size_t)row * CC2 + c * 8;
    float4 o0, o1;
    o0.x = __builtin_bit_cast(float, (unsigned)(unsigned short)v[0] << 16) + add;
    o0.y = __builtin_bit_cast(float, (unsigned)(unsigned short)v[1] << 16) + add;
    o0.z = __builtin_bit_cast(float, (unsigned)(unsigned short)v[2] << 16) + add;
    o0.w = __builtin_bit_cast(float, (unsigned)(unsigned short)v[3] << 16) + add;
    o1.x = __builtin_bit_cast(float, (unsigned)(unsigned short)v[4] << 16) + add;
    o1.y = __builtin_bit_cast(float, (unsigned)(unsigned short)v[5] << 16) + add;
    o1.z = __builtin_bit_cast(float, (unsigned)(unsigned short)v[6] << 16) + add;
    o1.w = __builtin_bit_cast(float, (unsigned)(unsigned short)v[7] << 16) + add;
    *(float4*)o = o0;
    *(float4*)(o + 4) = o1;
}

// ---------------- launch ----------------
extern "C" void kernel_launch(void* const* d_in, const int* in_sizes, int n_in,
                              void* d_out, int out_size, void* d_ws, size_t ws_size,
                              hipStream_t stream) {
    const float* x   = (const float*)d_in[0];
    const float* Wh  = (const float*)d_in[1];
    const float* bh  = (const float*)d_in[2];
    const float* W0a = (const float*)d_in[3];
    const float* W0b = (const float*)d_in[4];
    const float* W1a = (const float*)d_in[5];
    const float* W1b = (const float*)d_in[6];
    float* out = (float*)d_out;
    char*  ws  = (char*)d_ws;

    // padded row counts
    const int NH_P  = 2048;    // head rows, mult of 128
    const int N0_P  = 8192;    // tail0 proj rows, mult of 256
    const int N1_P  = 40192;   // tail1 proj rows, mult of 256 (157 tiles)

    size_t off = 0;
    auto alloc = [&](size_t bytes) { size_t o = off; off += (bytes + 255) & ~(size_t)255; return o; };
    ushort* x_bf   = (ushort*)(ws + alloc((size_t)BATCH * DH * 2));
    ushort* Wh_bf  = (ushort*)(ws + alloc((size_t)NH_P * DH * 2));
    ushort* W0a_bf = (ushort*)(ws + alloc((size_t)DH * DH * 2));
    ushort* W0b_bf = (ushort*)(ws + alloc((size_t)N0_P * DH * 2));
    ushort* W1a_bf = (ushort*)(ws + alloc((size_t)256 * DH * 2));
    ushort* W1b_bf = (ushort*)(ws + alloc((size_t)N1_P * 256 * 2));
    ushort* h0_bf  = (ushort*)(ws + alloc((size_t)BATCH * DH * 2));
    ushort* h1_bf  = (ushort*)(ws + alloc((size_t)BATCH * 256 * 2));
    float*  headL  = (float*)(ws + alloc((size_t)BATCH * OUT_HEAD * 4));
    float*  s01    = (float*)(ws + alloc((size_t)BATCH * 2 * 4));
    float*  rs0    = (float*)(ws + alloc((size_t)BATCH * 4));
    float*  rs1    = (float*)(ws + alloc((size_t)BATCH * 4));
    float*  add0   = (float*)(ws + alloc((size_t)BATCH * 4));
    float*  add1   = (float*)(ws + alloc((size_t)BATCH * 4));
    ushort* L0     = (ushort*)(ws + alloc((size_t)BATCH * N0_P * 2));

    convert_all_kernel<<<dim3(1280, 7), 256, 0, stream>>>(
        (const float4*)x,   (ushort4*)x_bf,   BATCH * DH / 4,        BATCH * DH / 4,
        (const float4*)Wh,  (ushort4*)Wh_bf,  OUT_HEAD * DH / 4,     NH_P * DH / 4,
        (const float4*)W0a, (ushort4*)W0a_bf, DH * DH / 4,           DH * DH / 4,
        (const float4*)W0b, (ushort4*)W0b_bf, (CC1 - CC0) * DH / 4,  N0_P * DH / 4,
        (const float4*)W1a, (ushort4*)W1a_bf, 256 * DH / 4,          256 * DH / 4,
        (const float4*)W1b, (ushort4*)W1b_bf, (CC2 - CC1) * 256 / 4, N1_P * 256 / 4,
        rs0, rs1);

    // fused: h0 (256 blocks) + h1 (64) + head (512)
    gemm128x3_kernel<<<832, 256, 0, stream>>>(
        x_bf, W0a_bf, h0_bf, W1a_bf, h1_bf, Wh_bf, headL);

    // head log-softmax -> out[:, :2000] + cluster scalars
    head_lsm_kernel<<<BATCH, 256, 0, stream>>>(headL, bh, out, s01);
    // tail0: bf16 logits (ws) + rowsum
    gemm256_kernel<1, true><<<dim3(N0_P / 256, BATCH / 256), 512, 0, stream>>>(
        h0_bf, W0b_bf, L0, BATCH, CC1 - CC0, DH, N0_P, rs0, nullptr);
    // tail1 pass1: rowsum only, no store
    gemm256_kernel<0, true><<<dim3(N1_P / 256, BATCH / 256), 512, 0, stream>>>(
        h1_bf, W1b_bf, nullptr, BATCH, CC2 - CC1, 256, 0, rs1, nullptr);
    // per-row additive constants
    prep_add_kernel<<<(BATCH + 255) / 256, 256, 0, stream>>>(s01, rs0, rs1, add0, add1, BATCH);
    // tail1 pass2: recompute, write normalized fp32 directly to out
    gemm256_kernel<3, false><<<dim3(N1_P / 256, BATCH / 256), 512, 0, stream>>>(
        h1_bf, W1b_bf, out + CC1, BATCH, CC2 - CC1, 256, CC2, nullptr, add1);
    // tail0: bf16 logits -> fp32 out with additive correction
    finalize_bf16_kernel<<<dim3((1000 + 255) / 256, BATCH), 256, 0, stream>>>(
        L0, N0_P, 1000, out + CC0, add0);
}